// Round 11
// baseline (1165.567 us; speedup 1.0000x reference)
//
#include <hip/hip_runtime.h>
#include <math.h>

typedef __attribute__((ext_vector_type(8))) short s8v;   // 8 x bf16
typedef __attribute__((ext_vector_type(4))) short s4v;   // 4 x bf16
typedef __attribute__((ext_vector_type(4))) float f4v;   // 4 x f32

static __device__ __forceinline__ unsigned short f2bf(float f) {
    union { float f; unsigned int u; } v; v.f = f;
    unsigned int r = v.u + 0x7fffu + ((v.u >> 16) & 1u);   // RNE
    return (unsigned short)(r >> 16);
}
static __device__ __forceinline__ float bf2f(unsigned short h) {
    union { unsigned int u; float f; } t; t.u = ((unsigned int)h) << 16;
    return t.f;
}

// ---------- split all weights to bf16 hi/lo planes ----------
// layout: [Win(32768) | Wh0 | Wh1 | Wh2 (262144 each) | Wout(32768)] = 851968
__global__ void conv_split(const float* __restrict__ Win, const float* __restrict__ Wh,
                           const float* __restrict__ Wout,
                           unsigned short* __restrict__ whi, unsigned short* __restrict__ wlo) {
    int i = blockIdx.x * 256 + threadIdx.x;
    if (i >= 851968) return;
    float v;
    if (i < 32768)       v = Win[i];
    else if (i < 819200) v = Wh[i - 32768];
    else                 v = Wout[i - 819200];
    unsigned short h = f2bf(v);
    whi[i] = h;
    wlo[i] = f2bf(v - bf2f(h));
}

// ---------- G0 = Wh0 @ W_in (512x64) fp32, + transposed bf16 copy ----------
__global__ void g0_kernel(const float* __restrict__ Wh0, const float* __restrict__ Win,
                          float* __restrict__ G0, unsigned short* __restrict__ G0tb) {
    int i = blockIdx.x;      // 0..511
    int j = threadIdx.x;     // 0..63
    float acc = 0.f;
    for (int k = 0; k < 512; ++k)
        acc = fmaf(Wh0[i * 512 + k], Win[k * 64 + j], acc);
    G0[i * 64 + j] = acc;
    G0tb[j * 512 + i] = f2bf(acc);
}

// ======== dual GEMM: z=0 -> fp32 vector path (t branch, sign-critical);
//          z=1 -> split-bf16 MFMA path (z branch, flip-tolerant). (R10-validated)
__global__ __launch_bounds__(256) void gemm_dual(
    const float* __restrict__ X0, const float* __restrict__ X1, int ldx,
    const float* __restrict__ W, int ldw,
    const unsigned short* __restrict__ Whi, const unsigned short* __restrict__ Wlo,
    const float* __restrict__ bias,
    float* __restrict__ C0, float* __restrict__ C1, int ldc,
    unsigned char* __restrict__ mo0, unsigned char* __restrict__ mo1,
    const unsigned char* __restrict__ mm0, const unsigned char* __restrict__ mm1,
    int K, int N, int mode)
{
    __shared__ __align__(16) unsigned char lds[30720];
    const int tid = threadIdx.x;
    const int m0 = blockIdx.x * 128;
    const int n0 = blockIdx.y * 64;

    if (blockIdx.z == 0) {
        const float* __restrict__ X = X0;
        float* __restrict__ C = C0;
        unsigned char* __restrict__ maskOut = mo0;
        const unsigned char* __restrict__ maskMul = mm0;
        float (*Xs)[132] = (float(*)[132])lds;
        float (*Ws)[68]  = (float(*)[68])(lds + 16896);
        const int tx = tid & 15, ty = tid >> 4;
        float acc[8][4] = {};
        float4 xr[4], wr[2];

        #define LOADCHUNK(k0)                                                        \
            {                                                                        \
                _Pragma("unroll")                                                    \
                for (int r = 0; r < 4; ++r) {                                        \
                    int idx = tid + r * 256;                                         \
                    int row = idx >> 3, kq = (idx & 7) * 4;                          \
                    xr[r] = *(const float4*)(X + (size_t)(m0 + row) * ldx + (k0) + kq); \
                }                                                                    \
                _Pragma("unroll")                                                    \
                for (int r = 0; r < 2; ++r) {                                        \
                    int idx = tid + r * 256;                                         \
                    int row = idx >> 3, kq = (idx & 7) * 4;                          \
                    wr[r] = *(const float4*)(W + (size_t)(n0 + row) * ldw + (k0) + kq); \
                }                                                                    \
            }
        #define STASH()                                                              \
            {                                                                        \
                _Pragma("unroll")                                                    \
                for (int r = 0; r < 4; ++r) {                                        \
                    int idx = tid + r * 256;                                         \
                    int row = idx >> 3, kq = (idx & 7) * 4;                          \
                    Xs[kq + 0][row] = xr[r].x; Xs[kq + 1][row] = xr[r].y;            \
                    Xs[kq + 2][row] = xr[r].z; Xs[kq + 3][row] = xr[r].w;            \
                }                                                                    \
                _Pragma("unroll")                                                    \
                for (int r = 0; r < 2; ++r) {                                        \
                    int idx = tid + r * 256;                                         \
                    int row = idx >> 3, kq = (idx & 7) * 4;                          \
                    Ws[kq + 0][row] = wr[r].x; Ws[kq + 1][row] = wr[r].y;            \
                    Ws[kq + 2][row] = wr[r].z; Ws[kq + 3][row] = wr[r].w;            \
                }                                                                    \
            }

        LOADCHUNK(0);
        STASH();
        __syncthreads();

        for (int k0 = 0; k0 < K; k0 += 32) {
            bool last = (k0 + 32 >= K);
            if (!last) LOADCHUNK(k0 + 32);
            #pragma unroll
            for (int kk = 0; kk < 32; ++kk) {
                float4 a0 = *(const float4*)&Xs[kk][ty * 4];
                float4 a1 = *(const float4*)&Xs[kk][64 + ty * 4];
                float4 b0 = *(const float4*)&Ws[kk][tx * 4];
                float av[8] = {a0.x, a0.y, a0.z, a0.w, a1.x, a1.y, a1.z, a1.w};
                float bv[4] = {b0.x, b0.y, b0.z, b0.w};
                #pragma unroll
                for (int i = 0; i < 8; ++i)
                    #pragma unroll
                    for (int j = 0; j < 4; ++j)
                        acc[i][j] = fmaf(av[i], bv[j], acc[i][j]);
            }
            __syncthreads();
            if (!last) {
                STASH();
                __syncthreads();
            }
        }

        float4 bb = {0, 0, 0, 0};
        if (mode & 1) bb = *(const float4*)(bias + n0 + tx * 4);
        const int c0 = n0 + tx * 4;
        #pragma unroll
        for (int i = 0; i < 8; ++i) {
            int r = m0 + ((i < 4) ? (ty * 4 + i) : (64 + ty * 4 + (i - 4)));
            float v[4];
            #pragma unroll
            for (int j = 0; j < 4; ++j) {
                v[j] = acc[i][j];
                if (mode & 1) v[j] += ((const float*)&bb)[j];
            }
            if (mode & 8) {
                uchar4 mo;
                mo.x = v[0] > 0.0f; mo.y = v[1] > 0.0f; mo.z = v[2] > 0.0f; mo.w = v[3] > 0.0f;
                *(uchar4*)&maskOut[(size_t)r * N + c0] = mo;
            }
            if (mode & 16) {
                uchar4 mm = *(const uchar4*)&maskMul[(size_t)r * N + c0];
                v[0] *= mm.x; v[1] *= mm.y; v[2] *= mm.z; v[3] *= mm.w;
            }
            if (mode & 2) {
                #pragma unroll
                for (int j = 0; j < 4; ++j) v[j] = fmaxf(v[j], 0.0f);
            }
            if (mode & 4) {
                float4 st = {v[0], v[1], v[2], v[3]};
                *(float4*)(C + (size_t)r * ldc + c0) = st;
            }
        }
    } else {
        const float* __restrict__ X = X1;
        float* __restrict__ C = C1;
        unsigned char* __restrict__ maskOut = mo1;
        const unsigned char* __restrict__ maskMul = mm1;
        unsigned short* Xh  = (unsigned short*)lds;
        unsigned short* Xl  = (unsigned short*)(lds + 10240);
        unsigned short* Wsh = (unsigned short*)(lds + 20480);
        unsigned short* Wsl = (unsigned short*)(lds + 25600);

        const int wave = tid >> 6, lane = tid & 63;
        const int q = lane >> 4, ln = lane & 15;
        const int wm = (wave & 1) * 64;
        const int wn = (wave >> 1) * 32;

        f4v acc[4][2];
        #pragma unroll
        for (int mt = 0; mt < 4; ++mt)
            #pragma unroll
            for (int nt = 0; nt < 2; ++nt)
                acc[mt][nt] = (f4v)(0.0f);

        float4 xr[4];
        s8v wh, wl;

        #define LOADD(k0)                                                              \
            {                                                                          \
                _Pragma("unroll")                                                      \
                for (int r = 0; r < 4; ++r) {                                          \
                    int idx = tid + r * 256;                                           \
                    int row = idx >> 3, kq = (idx & 7) * 4;                            \
                    xr[r] = *(const float4*)(X + (size_t)(m0 + row) * ldx + (k0) + kq); \
                }                                                                      \
                {                                                                      \
                    int row = tid >> 2, kc = (tid & 3) * 8;                            \
                    wh = *(const s8v*)(Whi + (size_t)(n0 + row) * ldw + (k0) + kc);    \
                    wl = *(const s8v*)(Wlo + (size_t)(n0 + row) * ldw + (k0) + kc);    \
                }                                                                      \
            }
        #define STASHD()                                                               \
            {                                                                          \
                _Pragma("unroll")                                                      \
                for (int r = 0; r < 4; ++r) {                                          \
                    int idx = tid + r * 256;                                           \
                    int row = idx >> 3, kq = (idx & 7) * 4;                            \
                    float a[4] = {xr[r].x, xr[r].y, xr[r].z, xr[r].w};                 \
                    s4v hv, lv;                                                        \
                    _Pragma("unroll")                                                  \
                    for (int j = 0; j < 4; ++j) {                                      \
                        unsigned short h = f2bf(a[j]);                                 \
                        hv[j] = (short)h;                                              \
                        lv[j] = (short)f2bf(a[j] - bf2f(h));                           \
                    }                                                                  \
                    *(s4v*)&Xh[row * 40 + kq] = hv;                                    \
                    *(s4v*)&Xl[row * 40 + kq] = lv;                                    \
                }                                                                      \
                {                                                                      \
                    int row = tid >> 2, kc = (tid & 3) * 8;                            \
                    *(s8v*)&Wsh[row * 40 + kc] = wh;                                   \
                    *(s8v*)&Wsl[row * 40 + kc] = wl;                                   \
                }                                                                      \
            }

        LOADD(0);
        STASHD();
        __syncthreads();

        for (int k0 = 0; k0 < K; k0 += 32) {
            bool last = (k0 + 32 >= K);
            if (!last) LOADD(k0 + 32);

            s8v ah[4], al[4], bh[2], bl[2];
            #pragma unroll
            for (int mt = 0; mt < 4; ++mt) {
                int rowm = wm + mt * 16 + ln;
                ah[mt] = *(const s8v*)&Xh[rowm * 40 + q * 8];
                al[mt] = *(const s8v*)&Xl[rowm * 40 + q * 8];
            }
            #pragma unroll
            for (int nt = 0; nt < 2; ++nt) {
                int rown = wn + nt * 16 + ln;
                bh[nt] = *(const s8v*)&Wsh[rown * 40 + q * 8];
                bl[nt] = *(const s8v*)&Wsl[rown * 40 + q * 8];
            }
            #pragma unroll
            for (int mt = 0; mt < 4; ++mt)
                #pragma unroll
                for (int nt = 0; nt < 2; ++nt) {
                    acc[mt][nt] = __builtin_amdgcn_mfma_f32_16x16x32_bf16(ah[mt], bh[nt], acc[mt][nt], 0, 0, 0);
                    acc[mt][nt] = __builtin_amdgcn_mfma_f32_16x16x32_bf16(ah[mt], bl[nt], acc[mt][nt], 0, 0, 0);
                    acc[mt][nt] = __builtin_amdgcn_mfma_f32_16x16x32_bf16(al[mt], bh[nt], acc[mt][nt], 0, 0, 0);
                }

            __syncthreads();
            if (!last) {
                STASHD();
                __syncthreads();
            }
        }

        #pragma unroll
        for (int nt = 0; nt < 2; ++nt) {
            int n = n0 + wn + nt * 16 + ln;
            float bv = (mode & 1) ? bias[n] : 0.0f;
            #pragma unroll
            for (int mt = 0; mt < 4; ++mt) {
                int mbase = m0 + wm + mt * 16 + q * 4;
                #pragma unroll
                for (int r = 0; r < 4; ++r) {
                    int m = mbase + r;
                    float v = acc[mt][nt][r] + bv;
                    if (mode & 8)  maskOut[(size_t)m * N + n] = (v > 0.0f) ? 1 : 0;
                    if (mode & 16) v *= (float)maskMul[(size_t)m * N + n];
                    if (mode & 2)  v = fmaxf(v, 0.0f);
                    if (mode & 4)  C[(size_t)m * ldc + n] = v;
                }
            }
        }
    }
}

// ======== fp32 GEMM 128x64 (R4-validated) — t-branch finals ========
__global__ __launch_bounds__(256) void gemm_nt(
    const float* __restrict__ X, int ldx,
    const float* __restrict__ W, int ldw,
    const float* __restrict__ bias,
    float* __restrict__ C, int ldc,
    unsigned char* __restrict__ maskOut,
    const unsigned char* __restrict__ maskMul,
    int K, int N, int mode)
{
    __shared__ float Xs[32][132];
    __shared__ float Ws[32][68];
    const int tid = threadIdx.x;
    const int m0 = blockIdx.x * 128;
    const int n0 = blockIdx.y * 64;
    const int tx = tid & 15, ty = tid >> 4;
    float acc[8][4] = {};
    float4 xr[4], wr[2];

    LOADCHUNK(0);
    STASH();
    __syncthreads();

    for (int k0 = 0; k0 < K; k0 += 32) {
        bool last = (k0 + 32 >= K);
        if (!last) LOADCHUNK(k0 + 32);
        #pragma unroll
        for (int kk = 0; kk < 32; ++kk) {
            float4 a0 = *(const float4*)&Xs[kk][ty * 4];
            float4 a1 = *(const float4*)&Xs[kk][64 + ty * 4];
            float4 b0 = *(const float4*)&Ws[kk][tx * 4];
            float av[8] = {a0.x, a0.y, a0.z, a0.w, a1.x, a1.y, a1.z, a1.w};
            float bv[4] = {b0.x, b0.y, b0.z, b0.w};
            #pragma unroll
            for (int i = 0; i < 8; ++i)
                #pragma unroll
                for (int j = 0; j < 4; ++j)
                    acc[i][j] = fmaf(av[i], bv[j], acc[i][j]);
        }
        __syncthreads();
        if (!last) {
            STASH();
            __syncthreads();
        }
    }

    float4 bb = {0, 0, 0, 0};
    if (mode & 1) bb = *(const float4*)(bias + n0 + tx * 4);
    const int c0 = n0 + tx * 4;
    #pragma unroll
    for (int i = 0; i < 8; ++i) {
        int r = m0 + ((i < 4) ? (ty * 4 + i) : (64 + ty * 4 + (i - 4)));
        float v[4];
        #pragma unroll
        for (int j = 0; j < 4; ++j) {
            v[j] = acc[i][j];
            if (mode & 1) v[j] += ((const float*)&bb)[j];
        }
        if (mode & 8) {
            uchar4 mo;
            mo.x = v[0] > 0.0f; mo.y = v[1] > 0.0f; mo.z = v[2] > 0.0f; mo.w = v[3] > 0.0f;
            *(uchar4*)&maskOut[(size_t)r * N + c0] = mo;
        }
        if (mode & 16) {
            uchar4 mm = *(const uchar4*)&maskMul[(size_t)r * N + c0];
            v[0] *= mm.x; v[1] *= mm.y; v[2] *= mm.z; v[3] *= mm.w;
        }
        if (mode & 2) {
            #pragma unroll
            for (int j = 0; j < 4; ++j) v[j] = fmaxf(v[j], 0.0f);
        }
        if (mode & 4) {
            float4 st = {v[0], v[1], v[2], v[3]};
            *(float4*)(C + (size_t)r * ldc + c0) = st;
        }
    }
}

// ======== split-bf16 MFMA GEMM (R9-validated) — V2,V3 ========
__global__ __launch_bounds__(128) void gemm3(
    const float* __restrict__ X, int ldx,
    const unsigned short* __restrict__ Whi, const unsigned short* __restrict__ Wlo, int ldw,
    float* __restrict__ C, int ldc,
    const unsigned char* __restrict__ maskMul,
    int K, int N, int mode)
{
    __shared__ __align__(16) unsigned short Xh[128 * 40];
    __shared__ __align__(16) unsigned short Xl[128 * 40];
    __shared__ __align__(16) unsigned short Wsh[64 * 40];
    __shared__ __align__(16) unsigned short Wsl[64 * 40];

    const int tid = threadIdx.x;
    const int m0 = blockIdx.x * 128;
    const int n0 = blockIdx.y * 64;
    const int wave = tid >> 6, lane = tid & 63;
    const int q = lane >> 4, ln = lane & 15;

    f4v acc[4][4];
    #pragma unroll
    for (int mt = 0; mt < 4; ++mt)
        #pragma unroll
        for (int nt = 0; nt < 4; ++nt)
            acc[mt][nt] = (f4v)(0.0f);

    float4 xr[8];
    s8v wh[2], wl[2];

    #define LOADC3(k0)                                                             \
        {                                                                          \
            _Pragma("unroll")                                                      \
            for (int r = 0; r < 8; ++r) {                                          \
                int idx = tid + r * 128;                                           \
                int row = idx >> 3, kq = (idx & 7) * 4;                            \
                xr[r] = *(const float4*)(X + (size_t)(m0 + row) * ldx + (k0) + kq); \
            }                                                                      \
            _Pragma("unroll")                                                      \
            for (int r = 0; r < 2; ++r) {                                          \
                int idx = tid + r * 128;                                           \
                int row = idx >> 2, kc = (idx & 3) * 8;                            \
                wh[r] = *(const s8v*)(Whi + (size_t)(n0 + row) * ldw + (k0) + kc); \
                wl[r] = *(const s8v*)(Wlo + (size_t)(n0 + row) * ldw + (k0) + kc); \
            }                                                                      \
        }
    #define STASH3()                                                               \
        {                                                                          \
            _Pragma("unroll")                                                      \
            for (int r = 0; r < 8; ++r) {                                          \
                int idx = tid + r * 128;                                           \
                int row = idx >> 3, kq = (idx & 7) * 4;                            \
                float a[4] = {xr[r].x, xr[r].y, xr[r].z, xr[r].w};                 \
                s4v hv, lv;                                                        \
                _Pragma("unroll")                                                  \
                for (int j = 0; j < 4; ++j) {                                      \
                    unsigned short h = f2bf(a[j]);                                 \
                    hv[j] = (short)h;                                              \
                    lv[j] = (short)f2bf(a[j] - bf2f(h));                           \
                }                                                                  \
                *(s4v*)&Xh[row * 40 + kq] = hv;                                    \
                *(s4v*)&Xl[row * 40 + kq] = lv;                                    \
            }                                                                      \
            _Pragma("unroll")                                                      \
            for (int r = 0; r < 2; ++r) {                                          \
                int idx = tid + r * 128;                                           \
                int row = idx >> 2, kc = (idx & 3) * 8;                            \
                *(s8v*)&Wsh[row * 40 + kc] = wh[r];                                \
                *(s8v*)&Wsl[row * 40 + kc] = wl[r];                                \
            }                                                                      \
        }

    LOADC3(0);
    STASH3();
    __syncthreads();

    for (int k0 = 0; k0 < K; k0 += 32) {
        bool last = (k0 + 32 >= K);
        if (!last) LOADC3(k0 + 32);

        s8v ah[4], al[4], bh[4], bl[4];
        #pragma unroll
        for (int mt = 0; mt < 4; ++mt) {
            int rowm = wave * 64 + mt * 16 + ln;
            ah[mt] = *(const s8v*)&Xh[rowm * 40 + q * 8];
            al[mt] = *(const s8v*)&Xl[rowm * 40 + q * 8];
        }
        #pragma unroll
        for (int nt = 0; nt < 4; ++nt) {
            int rown = nt * 16 + ln;
            bh[nt] = *(const s8v*)&Wsh[rown * 40 + q * 8];
            bl[nt] = *(const s8v*)&Wsl[rown * 40 + q * 8];
        }
        #pragma unroll
        for (int mt = 0; mt < 4; ++mt)
            #pragma unroll
            for (int nt = 0; nt < 4; ++nt) {
                acc[mt][nt] = __builtin_amdgcn_mfma_f32_16x16x32_bf16(ah[mt], bh[nt], acc[mt][nt], 0, 0, 0);
                acc[mt][nt] = __builtin_amdgcn_mfma_f32_16x16x32_bf16(ah[mt], bl[nt], acc[mt][nt], 0, 0, 0);
                acc[mt][nt] = __builtin_amdgcn_mfma_f32_16x16x32_bf16(al[mt], bh[nt], acc[mt][nt], 0, 0, 0);
            }

        __syncthreads();
        if (!last) {
            STASH3();
            __syncthreads();
        }
    }

    #pragma unroll
    for (int nt = 0; nt < 4; ++nt) {
        int n = n0 + nt * 16 + ln;
        #pragma unroll
        for (int mt = 0; mt < 4; ++mt) {
            int mbase = m0 + wave * 64 + mt * 16 + q * 4;
            #pragma unroll
            for (int r = 0; r < 4; ++r) {
                int m = mbase + r;
                float v = acc[mt][nt][r];
                if (mode & 16) v *= (float)maskMul[(size_t)m * N + n];
                if (mode & 2)  v = fmaxf(v, 0.0f);
                if (mode & 4)  C[(size_t)m * ldc + n] = v;
            }
        }
    }
}

// ---------- zng: bf16 MFMA Jacobian chain, 2 elems/block, 1024 threads (16 waves) ----------
// Same math/LDS layout as R10 (swizzled Rt); wave tile 64m x 32n, n-half = wave>>3.
// No A prefetch; 4 waves/SIMD TLP hides latency. VGPR must stay <=128 (16 resident waves).
__global__ __launch_bounds__(1024, 1) void zng_kernel(
    const unsigned short* __restrict__ whbf,   // [2][512][512] bf16 (layers 1,2)
    const unsigned short* __restrict__ woutbf, // [64][512] bf16
    const unsigned short* __restrict__ G0tb,   // [64][512] bf16 (G0 transposed)
    const unsigned char* __restrict__ mz1,
    const unsigned char* __restrict__ mz2,
    const unsigned char* __restrict__ mz3,
    float* __restrict__ out)                   // (4096,192), writes cols 128..191
{
    __shared__ __align__(16) unsigned short Rt[2][64 * 512]; // swizzled, no pad
    __shared__ unsigned char m2s[2][512];
    __shared__ unsigned char m3s[2][512];

    const int b0  = blockIdx.x * 2;
    const int tid = threadIdx.x;

    {
        int bb = tid >> 9, k = tid & 511;
        m2s[bb][k] = mz2[(size_t)(b0 + bb) * 512 + k];
        m3s[bb][k] = mz3[(size_t)(b0 + bb) * 512 + k];
    }
    // Phase A: Rt[bb][n][swz(ch)] = bf16(G0t[n][ch*8..]) * D1_bb
    #pragma unroll 4
    for (int i = 0; i < 8; ++i) {
        int c = i * 1024 + tid;            // 0..8191
        int bb = c >> 12, rem = c & 4095;
        int n = rem >> 6, ch = rem & 63;
        int k = ch * 8;
        s8v g = *(const s8v*)(G0tb + n * 512 + k);
        const unsigned char* mm = mz1 + (size_t)(b0 + bb) * 512 + k;
        unsigned int mlo = *(const unsigned int*)(mm);
        unsigned int mhi = *(const unsigned int*)(mm + 4);
        s8v r;
        #pragma unroll
        for (int j = 0; j < 4; ++j) r[j] = ((mlo >> (8 * j)) & 1) ? g[j] : (short)0;
        #pragma unroll
        for (int j = 0; j < 4; ++j) r[4 + j] = ((mhi >> (8 * j)) & 1) ? g[4 + j] : (short)0;
        *(s8v*)(&Rt[bb][n * 512 + ((ch ^ (n & 7)) << 3)]) = r;
    }
    __syncthreads();

    const int lane = tid & 63, wave = tid >> 6;   // wave 0..15
    const int q = lane >> 4, ln = lane & 15;
    const int ln7 = ln & 7;
    const int w8 = wave & 7;                      // m-group
    const int nh = wave >> 3;                     // n-half (0/1)

    // stages: Out_b = Wh[s+1] @ R_b ; R_b <- (D[s+2] (.) Out_b)^T
    for (int s = 0; s < 2; ++s) {
        const unsigned short* A = whbf + (size_t)s * 262144;
        f4v acc[2][4][2];                         // [bb][mt][nt] : 64 VGPRs
        #pragma unroll
        for (int bb = 0; bb < 2; ++bb)
            #pragma unroll
            for (int mt = 0; mt < 4; ++mt)
                #pragma unroll
                for (int nt = 0; nt < 2; ++nt)
                    acc[bb][mt][nt] = (f4v)(0.0f);

        for (int ks = 0; ks < 16; ++ks) {
            int kA = ks * 32 + q * 8;
            s8v af[4];
            #pragma unroll
            for (int mt = 0; mt < 4; ++mt)
                af[mt] = *(const s8v*)(A + (size_t)(w8 * 64 + mt * 16 + ln) * 512 + kA);

            int cB = (ks * 4 + q) ^ ln7;          // swizzled chunk index
            s8v bfr[2][2];
            #pragma unroll
            for (int bb = 0; bb < 2; ++bb)
                #pragma unroll
                for (int nt = 0; nt < 2; ++nt)
                    bfr[bb][nt] = *(const s8v*)(&Rt[bb][(nh * 32 + nt * 16 + ln) * 512 + (cB << 3)]);

            #pragma unroll
            for (int mt = 0; mt < 4; ++mt)
                #pragma unroll
                for (int nt = 0; nt < 2; ++nt) {
                    acc[0][mt][nt] = __builtin_amdgcn_mfma_f32_16x16x32_bf16(af[mt], bfr[0][nt], acc[0][mt][nt], 0, 0, 0);
                    acc[1][mt][nt] = __builtin_amdgcn_mfma_f32_16x16x32_bf16(af[mt], bfr[1][nt], acc[1][mt][nt], 0, 0, 0);
                }
        }
        __syncthreads();   // all reads of old Rt done

        const unsigned char (*msk)[512] = (s == 0) ? m2s : m3s;
        #pragma unroll
        for (int bb = 0; bb < 2; ++bb)
            #pragma unroll
            for (int mt = 0; mt < 4; ++mt) {
                int m0 = w8 * 64 + mt * 16 + q * 4;      // k-position in new R
                int cw = (w8 * 8 + mt * 2 + (q >> 1));   // chunk of m0
                int wo = (q & 1) * 4;                    // short offset in chunk
                uchar4 mv = *(const uchar4*)&msk[bb][m0];
                unsigned char mb[4] = {mv.x, mv.y, mv.z, mv.w};
                #pragma unroll
                for (int nt = 0; nt < 2; ++nt) {
                    int n = nh * 32 + nt * 16 + ln;
                    s4v pk;
                    #pragma unroll
                    for (int r = 0; r < 4; ++r) {
                        float v = mb[r] ? acc[bb][mt][nt][r] : 0.0f;
                        pk[r] = (short)f2bf(v);
                    }
                    *(s4v*)(&Rt[bb][n * 512 + ((cw ^ ln7) << 3) + wo]) = pk;
                }
            }
        __syncthreads();
    }

    // final: g_b = Wout @ R3_b (64x64); zng[m] = ||g_b[m,:]|| — waves 0..7 (R10 form)
    if (wave < 8) {
        const int bb = wave >> 2, w4 = wave & 3;
        f4v acc3[4];
        #pragma unroll
        for (int nt = 0; nt < 4; ++nt) acc3[nt] = (f4v)(0.0f);
        for (int ks = 0; ks < 16; ++ks) {
            int kA = ks * 32 + q * 8;
            int cB = (ks * 4 + q) ^ ln7;
            s8v af = *(const s8v*)(woutbf + (size_t)(w4 * 16 + ln) * 512 + kA);
            #pragma unroll
            for (int nt = 0; nt < 4; ++nt) {
                s8v bfr = *(const s8v*)(&Rt[bb][(nt * 16 + ln) * 512 + (cB << 3)]);
                acc3[nt] = __builtin_amdgcn_mfma_f32_16x16x32_bf16(af, bfr, acc3[nt], 0, 0, 0);
            }
        }
        float ss[4];
        #pragma unroll
        for (int r = 0; r < 4; ++r) {
            float s = 0.f;
            #pragma unroll
            for (int nt = 0; nt < 4; ++nt) { float v = acc3[nt][r]; s = fmaf(v, v, s); }
            ss[r] = s;
        }
        #pragma unroll
        for (int off = 1; off < 16; off <<= 1)
            #pragma unroll
            for (int r = 0; r < 4; ++r)
                ss[r] += __shfl_xor(ss[r], off, 64);
        if (ln == 0) {
            #pragma unroll
            for (int r = 0; r < 4; ++r)
                out[(size_t)(b0 + bb) * 192 + 128 + w4 * 16 + q * 4 + r] = sqrtf(ss[r]);
        }
    }
}

// ---------- host ----------
extern "C" void kernel_launch(void* const* d_in, const int* in_sizes, int n_in,
                              void* d_out, int out_size, void* d_ws, size_t ws_size,
                              hipStream_t stream) {
    const float* x    = (const float*)d_in[0];
    const float* Win  = (const float*)d_in[1];
    const float* bin  = (const float*)d_in[2];
    const float* Wh   = (const float*)d_in[3];
    const float* bh   = (const float*)d_in[4];
    const float* Wout = (const float*)d_in[5];
    const float* bout = (const float*)d_in[6];
    float* out = (float*)d_out;

    char* ws = (char*)d_ws;
    unsigned short* whi  = (unsigned short*)(ws);                   // 1703936 B
    unsigned short* wlo  = (unsigned short*)(ws + 1703936);         // 1703936 B
    float*          G0   = (float*)(ws + 3407872);                  // 131072 B
    unsigned short* G0tb = (unsigned short*)(ws + 3538944);         // 65536 B
    unsigned char*  masks = (unsigned char*)(ws + 3604480);         // 6 * 2 MB
    unsigned char* mt1 = masks + 0 * 2097152;
    unsigned char* mt2 = masks + 1 * 2097152;
    unsigned char* mt3 = masks + 2 * 2097152;
    unsigned char* mz1 = masks + 3 * 2097152;
    unsigned char* mz2 = masks + 4 * 2097152;
    unsigned char* mz3 = masks + 5 * 2097152;
    float* bufs = (float*)(ws + 3604480 + 12582912);                // 4 x 8 MB
    float* tA = bufs + 0 * 2097152;
    float* tB = bufs + 1 * 2097152;
    float* zA = bufs + 2 * 2097152;
    float* zB = bufs + 3 * 2097152;

    // hi/lo plane offsets (elems): [Win@0 | Wh0@32768 | Wh1@294912 | Wh2@557056 | Wout@819200]
    const unsigned short* WinH  = whi,          *WinL  = wlo;
    const unsigned short* Wh0H  = whi + 32768,  *Wh0L  = wlo + 32768;
    const unsigned short* Wh1H  = whi + 294912, *Wh1L  = wlo + 294912;
    const unsigned short* Wh2H  = whi + 557056, *Wh2L  = wlo + 557056;
    const unsigned short* WoutH = whi + 819200;

    const float* Wh0 = Wh;
    const float* Wh1 = Wh + 262144;
    const float* Wh2 = Wh + 524288;
    const float* bh0 = bh, *bh1 = bh + 512, *bh2 = bh + 1024;

    conv_split<<<dim3(3328), dim3(256), 0, stream>>>(Win, Wh, Wout, whi, wlo);
    g0_kernel<<<dim3(512), dim3(64), 0, stream>>>(Wh0, Win, G0, G0tb);

    auto gdual = [&](const float* X0, const float* X1, int ldx,
                     const float* W, const unsigned short* WH, const unsigned short* WL, int ldw,
                     const float* bias, float* C0, float* C1, int ldc,
                     unsigned char* mo0, unsigned char* mo1,
                     const unsigned char* mm0, const unsigned char* mm1,
                     int K, int N, int mode) {
        dim3 g(4096 / 128, N / 64, 2);
        gemm_dual<<<g, dim3(256), 0, stream>>>(X0, X1, ldx, W, ldw, WH, WL, bias,
                                               C0, C1, ldc, mo0, mo1, mm0, mm1, K, N, mode);
    };
    auto gemm1 = [&](const float* X, int ldx, const float* W, int ldw, const float* bias,
                     float* C, int ldc, unsigned char* mo, const unsigned char* mm,
                     int K, int N, int mode) {
        dim3 g(4096 / 128, N / 64, 1);
        gemm_nt<<<g, dim3(256), 0, stream>>>(X, ldx, W, ldw, bias, C, ldc, mo, mm, K, N, mode);
    };
    auto g3 = [&](const float* X, int ldx,
                  const unsigned short* WH, const unsigned short* WL, int ldw,
                  float* C, int ldc, const unsigned char* mm, int K, int N, int mode) {
        dim3 g(4096 / 128, N / 64, 1);
        gemm3<<<g, dim3(128), 0, stream>>>(X, ldx, WH, WL, ldw, C, ldc, mm, K, N, mode);
    };

    // ---- fused forward + delta chain (t fp32 ; z split-bf16 MFMA) ----
    gdual(x, x + 128, 192, Win, WinH, WinL, 64, bin, tA, zA, 512, 0, 0, 0, 0, 64, 512, 1 | 4);        // h0
    gdual(tA, zA, 512, Wh0, Wh0H, Wh0L, 512, bh0,   tB, zB, 512, 0, 0, 0, 0, 512, 512, 1 | 2 | 4);    // h1
    gdual(tB, zB, 512, Wh0, Wh0H, Wh0L, 512, bh0,   0, 0, 0, mt1, mz1, 0, 0, 512, 512, 1 | 8);        // delta1
    gdual(tB, zB, 512, Wh1, Wh1H, Wh1L, 512, bh1,   tA, zA, 512, 0, 0, 0, 0, 512, 512, 1 | 2 | 4);    // h2
    gdual(tA, zA, 512, Wh1, Wh1H, Wh1L, 512, bh1,   0, 0, 0, mt2, mz2, 0, 0, 512, 512, 1 | 8);        // delta2
    gdual(tA, zA, 512, Wh2, Wh2H, Wh2L, 512, bh2,   tB, zB, 512, 0, 0, 0, 0, 512, 512, 1 | 2 | 4);    // h3
    gdual(tB, zB, 512, Wh2, Wh2H, Wh2L, 512, bh2,   0, 0, 0, mt3, mz3, 0, 0, 512, 512, 1 | 8);        // delta3

    // ---- zng (z-branch Jacobian row norms), 2 elems/block, 1024 threads ----
    zng_kernel<<<dim3(2048), dim3(1024), 0, stream>>>(Wh1H, WoutH, G0tb, mz1, mz2, mz3, out);

    // ---- h_out (t-branch forward output) — fp32 ----
    gemm1(tB, 512, Wout, 512, bout, out, 192, 0, 0, 512, 64, 1 | 4);                                  // cols 0..63

    // ---- h_dot chain: V = D (.) (W v) ----
    gemm1(x + 64, 192, G0, 64, 0, tA, 512, 0, mt1, 64, 512, 4 | 16);                                  // V1 (fp32)
    g3(tA, 512, Wh1H, Wh1L, 512, zA, 512, mt2, 512, 512, 4 | 16);                                     // V2 (split-bf16)
    g3(zA, 512, Wh2H, Wh2L, 512, zB, 512, mt3, 512, 512, 4 | 16);                                     // V3 (split-bf16)
    gemm1(zB, 512, Wout, 512, 0, out + 64, 192, 0, 0, 512, 64, 4);                                    // h_dot (fp32)
}

// Round 12
// 1163.131 us; speedup vs baseline: 1.0021x; 1.0021x over previous
//
#include <hip/hip_runtime.h>
#include <math.h>

typedef __attribute__((ext_vector_type(8))) short s8v;   // 8 x bf16
typedef __attribute__((ext_vector_type(4))) short s4v;   // 4 x bf16
typedef __attribute__((ext_vector_type(4))) float f4v;   // 4 x f32

static __device__ __forceinline__ unsigned short f2bf(float f) {
    union { float f; unsigned int u; } v; v.f = f;
    unsigned int r = v.u + 0x7fffu + ((v.u >> 16) & 1u);   // RNE
    return (unsigned short)(r >> 16);
}
static __device__ __forceinline__ float bf2f(unsigned short h) {
    union { unsigned int u; float f; } t; t.u = ((unsigned int)h) << 16;
    return t.f;
}

// ---------- split all weights to bf16 hi/lo planes ----------
// layout: [Win(32768) | Wh0 | Wh1 | Wh2 (262144 each) | Wout(32768)] = 851968
__global__ void conv_split(const float* __restrict__ Win, const float* __restrict__ Wh,
                           const float* __restrict__ Wout,
                           unsigned short* __restrict__ whi, unsigned short* __restrict__ wlo) {
    int i = blockIdx.x * 256 + threadIdx.x;
    if (i >= 851968) return;
    float v;
    if (i < 32768)       v = Win[i];
    else if (i < 819200) v = Wh[i - 32768];
    else                 v = Wout[i - 819200];
    unsigned short h = f2bf(v);
    whi[i] = h;
    wlo[i] = f2bf(v - bf2f(h));
}

// ---------- G0 = Wh0 @ W_in (512x64) fp32, + transposed bf16 copy ----------
__global__ void g0_kernel(const float* __restrict__ Wh0, const float* __restrict__ Win,
                          float* __restrict__ G0, unsigned short* __restrict__ G0tb) {
    int i = blockIdx.x;      // 0..511
    int j = threadIdx.x;     // 0..63
    float acc = 0.f;
    for (int k = 0; k < 512; ++k)
        acc = fmaf(Wh0[i * 512 + k], Win[k * 64 + j], acc);
    G0[i * 64 + j] = acc;
    G0tb[j * 512 + i] = f2bf(acc);
}

// ======== dual GEMM: z=0 -> fp32 vector path (t branch, sign-critical);
//          z=1 -> split-bf16 MFMA path (z branch, flip-tolerant). (R10-validated)
__global__ __launch_bounds__(256) void gemm_dual(
    const float* __restrict__ X0, const float* __restrict__ X1, int ldx,
    const float* __restrict__ W, int ldw,
    const unsigned short* __restrict__ Whi, const unsigned short* __restrict__ Wlo,
    const float* __restrict__ bias,
    float* __restrict__ C0, float* __restrict__ C1, int ldc,
    unsigned char* __restrict__ mo0, unsigned char* __restrict__ mo1,
    const unsigned char* __restrict__ mm0, const unsigned char* __restrict__ mm1,
    int K, int N, int mode)
{
    __shared__ __align__(16) unsigned char lds[30720];
    const int tid = threadIdx.x;
    const int m0 = blockIdx.x * 128;
    const int n0 = blockIdx.y * 64;

    if (blockIdx.z == 0) {
        const float* __restrict__ X = X0;
        float* __restrict__ C = C0;
        unsigned char* __restrict__ maskOut = mo0;
        const unsigned char* __restrict__ maskMul = mm0;
        float (*Xs)[132] = (float(*)[132])lds;
        float (*Ws)[68]  = (float(*)[68])(lds + 16896);
        const int tx = tid & 15, ty = tid >> 4;
        float acc[8][4] = {};
        float4 xr[4], wr[2];

        #define LOADCHUNK(k0)                                                        \
            {                                                                        \
                _Pragma("unroll")                                                    \
                for (int r = 0; r < 4; ++r) {                                        \
                    int idx = tid + r * 256;                                         \
                    int row = idx >> 3, kq = (idx & 7) * 4;                          \
                    xr[r] = *(const float4*)(X + (size_t)(m0 + row) * ldx + (k0) + kq); \
                }                                                                    \
                _Pragma("unroll")                                                    \
                for (int r = 0; r < 2; ++r) {                                        \
                    int idx = tid + r * 256;                                         \
                    int row = idx >> 3, kq = (idx & 7) * 4;                          \
                    wr[r] = *(const float4*)(W + (size_t)(n0 + row) * ldw + (k0) + kq); \
                }                                                                    \
            }
        #define STASH()                                                              \
            {                                                                        \
                _Pragma("unroll")                                                    \
                for (int r = 0; r < 4; ++r) {                                        \
                    int idx = tid + r * 256;                                         \
                    int row = idx >> 3, kq = (idx & 7) * 4;                          \
                    Xs[kq + 0][row] = xr[r].x; Xs[kq + 1][row] = xr[r].y;            \
                    Xs[kq + 2][row] = xr[r].z; Xs[kq + 3][row] = xr[r].w;            \
                }                                                                    \
                _Pragma("unroll")                                                    \
                for (int r = 0; r < 2; ++r) {                                        \
                    int idx = tid + r * 256;                                         \
                    int row = idx >> 3, kq = (idx & 7) * 4;                          \
                    Ws[kq + 0][row] = wr[r].x; Ws[kq + 1][row] = wr[r].y;            \
                    Ws[kq + 2][row] = wr[r].z; Ws[kq + 3][row] = wr[r].w;            \
                }                                                                    \
            }

        LOADCHUNK(0);
        STASH();
        __syncthreads();

        for (int k0 = 0; k0 < K; k0 += 32) {
            bool last = (k0 + 32 >= K);
            if (!last) LOADCHUNK(k0 + 32);
            #pragma unroll
            for (int kk = 0; kk < 32; ++kk) {
                float4 a0 = *(const float4*)&Xs[kk][ty * 4];
                float4 a1 = *(const float4*)&Xs[kk][64 + ty * 4];
                float4 b0 = *(const float4*)&Ws[kk][tx * 4];
                float av[8] = {a0.x, a0.y, a0.z, a0.w, a1.x, a1.y, a1.z, a1.w};
                float bv[4] = {b0.x, b0.y, b0.z, b0.w};
                #pragma unroll
                for (int i = 0; i < 8; ++i)
                    #pragma unroll
                    for (int j = 0; j < 4; ++j)
                        acc[i][j] = fmaf(av[i], bv[j], acc[i][j]);
            }
            __syncthreads();
            if (!last) {
                STASH();
                __syncthreads();
            }
        }

        float4 bb = {0, 0, 0, 0};
        if (mode & 1) bb = *(const float4*)(bias + n0 + tx * 4);
        const int c0 = n0 + tx * 4;
        #pragma unroll
        for (int i = 0; i < 8; ++i) {
            int r = m0 + ((i < 4) ? (ty * 4 + i) : (64 + ty * 4 + (i - 4)));
            float v[4];
            #pragma unroll
            for (int j = 0; j < 4; ++j) {
                v[j] = acc[i][j];
                if (mode & 1) v[j] += ((const float*)&bb)[j];
            }
            if (mode & 8) {
                uchar4 mo;
                mo.x = v[0] > 0.0f; mo.y = v[1] > 0.0f; mo.z = v[2] > 0.0f; mo.w = v[3] > 0.0f;
                *(uchar4*)&maskOut[(size_t)r * N + c0] = mo;
            }
            if (mode & 16) {
                uchar4 mm = *(const uchar4*)&maskMul[(size_t)r * N + c0];
                v[0] *= mm.x; v[1] *= mm.y; v[2] *= mm.z; v[3] *= mm.w;
            }
            if (mode & 2) {
                #pragma unroll
                for (int j = 0; j < 4; ++j) v[j] = fmaxf(v[j], 0.0f);
            }
            if (mode & 4) {
                float4 st = {v[0], v[1], v[2], v[3]};
                *(float4*)(C + (size_t)r * ldc + c0) = st;
            }
        }
    } else {
        const float* __restrict__ X = X1;
        float* __restrict__ C = C1;
        unsigned char* __restrict__ maskOut = mo1;
        const unsigned char* __restrict__ maskMul = mm1;
        unsigned short* Xh  = (unsigned short*)lds;
        unsigned short* Xl  = (unsigned short*)(lds + 10240);
        unsigned short* Wsh = (unsigned short*)(lds + 20480);
        unsigned short* Wsl = (unsigned short*)(lds + 25600);

        const int wave = tid >> 6, lane = tid & 63;
        const int q = lane >> 4, ln = lane & 15;
        const int wm = (wave & 1) * 64;
        const int wn = (wave >> 1) * 32;

        f4v acc[4][2];
        #pragma unroll
        for (int mt = 0; mt < 4; ++mt)
            #pragma unroll
            for (int nt = 0; nt < 2; ++nt)
                acc[mt][nt] = (f4v)(0.0f);

        float4 xr[4];
        s8v wh, wl;

        #define LOADD(k0)                                                              \
            {                                                                          \
                _Pragma("unroll")                                                      \
                for (int r = 0; r < 4; ++r) {                                          \
                    int idx = tid + r * 256;                                           \
                    int row = idx >> 3, kq = (idx & 7) * 4;                            \
                    xr[r] = *(const float4*)(X + (size_t)(m0 + row) * ldx + (k0) + kq); \
                }                                                                      \
                {                                                                      \
                    int row = tid >> 2, kc = (tid & 3) * 8;                            \
                    wh = *(const s8v*)(Whi + (size_t)(n0 + row) * ldw + (k0) + kc);    \
                    wl = *(const s8v*)(Wlo + (size_t)(n0 + row) * ldw + (k0) + kc);    \
                }                                                                      \
            }
        #define STASHD()                                                               \
            {                                                                          \
                _Pragma("unroll")                                                      \
                for (int r = 0; r < 4; ++r) {                                          \
                    int idx = tid + r * 256;                                           \
                    int row = idx >> 3, kq = (idx & 7) * 4;                            \
                    float a[4] = {xr[r].x, xr[r].y, xr[r].z, xr[r].w};                 \
                    s4v hv, lv;                                                        \
                    _Pragma("unroll")                                                  \
                    for (int j = 0; j < 4; ++j) {                                      \
                        unsigned short h = f2bf(a[j]);                                 \
                        hv[j] = (short)h;                                              \
                        lv[j] = (short)f2bf(a[j] - bf2f(h));                           \
                    }                                                                  \
                    *(s4v*)&Xh[row * 40 + kq] = hv;                                    \
                    *(s4v*)&Xl[row * 40 + kq] = lv;                                    \
                }                                                                      \
                {                                                                      \
                    int row = tid >> 2, kc = (tid & 3) * 8;                            \
                    *(s8v*)&Wsh[row * 40 + kc] = wh;                                   \
                    *(s8v*)&Wsl[row * 40 + kc] = wl;                                   \
                }                                                                      \
            }

        LOADD(0);
        STASHD();
        __syncthreads();

        for (int k0 = 0; k0 < K; k0 += 32) {
            bool last = (k0 + 32 >= K);
            if (!last) LOADD(k0 + 32);

            s8v ah[4], al[4], bh[2], bl[2];
            #pragma unroll
            for (int mt = 0; mt < 4; ++mt) {
                int rowm = wm + mt * 16 + ln;
                ah[mt] = *(const s8v*)&Xh[rowm * 40 + q * 8];
                al[mt] = *(const s8v*)&Xl[rowm * 40 + q * 8];
            }
            #pragma unroll
            for (int nt = 0; nt < 2; ++nt) {
                int rown = wn + nt * 16 + ln;
                bh[nt] = *(const s8v*)&Wsh[rown * 40 + q * 8];
                bl[nt] = *(const s8v*)&Wsl[rown * 40 + q * 8];
            }
            #pragma unroll
            for (int mt = 0; mt < 4; ++mt)
                #pragma unroll
                for (int nt = 0; nt < 2; ++nt) {
                    acc[mt][nt] = __builtin_amdgcn_mfma_f32_16x16x32_bf16(ah[mt], bh[nt], acc[mt][nt], 0, 0, 0);
                    acc[mt][nt] = __builtin_amdgcn_mfma_f32_16x16x32_bf16(ah[mt], bl[nt], acc[mt][nt], 0, 0, 0);
                    acc[mt][nt] = __builtin_amdgcn_mfma_f32_16x16x32_bf16(al[mt], bh[nt], acc[mt][nt], 0, 0, 0);
                }

            __syncthreads();
            if (!last) {
                STASHD();
                __syncthreads();
            }
        }

        #pragma unroll
        for (int nt = 0; nt < 2; ++nt) {
            int n = n0 + wn + nt * 16 + ln;
            float bv = (mode & 1) ? bias[n] : 0.0f;
            #pragma unroll
            for (int mt = 0; mt < 4; ++mt) {
                int mbase = m0 + wm + mt * 16 + q * 4;
                #pragma unroll
                for (int r = 0; r < 4; ++r) {
                    int m = mbase + r;
                    float v = acc[mt][nt][r] + bv;
                    if (mode & 8)  maskOut[(size_t)m * N + n] = (v > 0.0f) ? 1 : 0;
                    if (mode & 16) v *= (float)maskMul[(size_t)m * N + n];
                    if (mode & 2)  v = fmaxf(v, 0.0f);
                    if (mode & 4)  C[(size_t)m * ldc + n] = v;
                }
            }
        }
    }
}

// ======== fp32 GEMM 128x64 (R4-validated) — t-branch finals ========
__global__ __launch_bounds__(256) void gemm_nt(
    const float* __restrict__ X, int ldx,
    const float* __restrict__ W, int ldw,
    const float* __restrict__ bias,
    float* __restrict__ C, int ldc,
    unsigned char* __restrict__ maskOut,
    const unsigned char* __restrict__ maskMul,
    int K, int N, int mode)
{
    __shared__ float Xs[32][132];
    __shared__ float Ws[32][68];
    const int tid = threadIdx.x;
    const int m0 = blockIdx.x * 128;
    const int n0 = blockIdx.y * 64;
    const int tx = tid & 15, ty = tid >> 4;
    float acc[8][4] = {};
    float4 xr[4], wr[2];

    LOADCHUNK(0);
    STASH();
    __syncthreads();

    for (int k0 = 0; k0 < K; k0 += 32) {
        bool last = (k0 + 32 >= K);
        if (!last) LOADCHUNK(k0 + 32);
        #pragma unroll
        for (int kk = 0; kk < 32; ++kk) {
            float4 a0 = *(const float4*)&Xs[kk][ty * 4];
            float4 a1 = *(const float4*)&Xs[kk][64 + ty * 4];
            float4 b0 = *(const float4*)&Ws[kk][tx * 4];
            float av[8] = {a0.x, a0.y, a0.z, a0.w, a1.x, a1.y, a1.z, a1.w};
            float bv[4] = {b0.x, b0.y, b0.z, b0.w};
            #pragma unroll
            for (int i = 0; i < 8; ++i)
                #pragma unroll
                for (int j = 0; j < 4; ++j)
                    acc[i][j] = fmaf(av[i], bv[j], acc[i][j]);
        }
        __syncthreads();
        if (!last) {
            STASH();
            __syncthreads();
        }
    }

    float4 bb = {0, 0, 0, 0};
    if (mode & 1) bb = *(const float4*)(bias + n0 + tx * 4);
    const int c0 = n0 + tx * 4;
    #pragma unroll
    for (int i = 0; i < 8; ++i) {
        int r = m0 + ((i < 4) ? (ty * 4 + i) : (64 + ty * 4 + (i - 4)));
        float v[4];
        #pragma unroll
        for (int j = 0; j < 4; ++j) {
            v[j] = acc[i][j];
            if (mode & 1) v[j] += ((const float*)&bb)[j];
        }
        if (mode & 8) {
            uchar4 mo;
            mo.x = v[0] > 0.0f; mo.y = v[1] > 0.0f; mo.z = v[2] > 0.0f; mo.w = v[3] > 0.0f;
            *(uchar4*)&maskOut[(size_t)r * N + c0] = mo;
        }
        if (mode & 16) {
            uchar4 mm = *(const uchar4*)&maskMul[(size_t)r * N + c0];
            v[0] *= mm.x; v[1] *= mm.y; v[2] *= mm.z; v[3] *= mm.w;
        }
        if (mode & 2) {
            #pragma unroll
            for (int j = 0; j < 4; ++j) v[j] = fmaxf(v[j], 0.0f);
        }
        if (mode & 4) {
            float4 st = {v[0], v[1], v[2], v[3]};
            *(float4*)(C + (size_t)r * ldc + c0) = st;
        }
    }
}

// ======== split-bf16 MFMA GEMM (R9-validated) — V2,V3 ========
__global__ __launch_bounds__(128) void gemm3(
    const float* __restrict__ X, int ldx,
    const unsigned short* __restrict__ Whi, const unsigned short* __restrict__ Wlo, int ldw,
    float* __restrict__ C, int ldc,
    const unsigned char* __restrict__ maskMul,
    int K, int N, int mode)
{
    __shared__ __align__(16) unsigned short Xh[128 * 40];
    __shared__ __align__(16) unsigned short Xl[128 * 40];
    __shared__ __align__(16) unsigned short Wsh[64 * 40];
    __shared__ __align__(16) unsigned short Wsl[64 * 40];

    const int tid = threadIdx.x;
    const int m0 = blockIdx.x * 128;
    const int n0 = blockIdx.y * 64;
    const int wave = tid >> 6, lane = tid & 63;
    const int q = lane >> 4, ln = lane & 15;

    f4v acc[4][4];
    #pragma unroll
    for (int mt = 0; mt < 4; ++mt)
        #pragma unroll
        for (int nt = 0; nt < 4; ++nt)
            acc[mt][nt] = (f4v)(0.0f);

    float4 xr[8];
    s8v wh[2], wl[2];

    #define LOADC3(k0)                                                             \
        {                                                                          \
            _Pragma("unroll")                                                      \
            for (int r = 0; r < 8; ++r) {                                          \
                int idx = tid + r * 128;                                           \
                int row = idx >> 3, kq = (idx & 7) * 4;                            \
                xr[r] = *(const float4*)(X + (size_t)(m0 + row) * ldx + (k0) + kq); \
            }                                                                      \
            _Pragma("unroll")                                                      \
            for (int r = 0; r < 2; ++r) {                                          \
                int idx = tid + r * 128;                                           \
                int row = idx >> 2, kc = (idx & 3) * 8;                            \
                wh[r] = *(const s8v*)(Whi + (size_t)(n0 + row) * ldw + (k0) + kc); \
                wl[r] = *(const s8v*)(Wlo + (size_t)(n0 + row) * ldw + (k0) + kc); \
            }                                                                      \
        }
    #define STASH3()                                                               \
        {                                                                          \
            _Pragma("unroll")                                                      \
            for (int r = 0; r < 8; ++r) {                                          \
                int idx = tid + r * 128;                                           \
                int row = idx >> 3, kq = (idx & 7) * 4;                            \
                float a[4] = {xr[r].x, xr[r].y, xr[r].z, xr[r].w};                 \
                s4v hv, lv;                                                        \
                _Pragma("unroll")                                                  \
                for (int j = 0; j < 4; ++j) {                                      \
                    unsigned short h = f2bf(a[j]);                                 \
                    hv[j] = (short)h;                                              \
                    lv[j] = (short)f2bf(a[j] - bf2f(h));                           \
                }                                                                  \
                *(s4v*)&Xh[row * 40 + kq] = hv;                                    \
                *(s4v*)&Xl[row * 40 + kq] = lv;                                    \
            }                                                                      \
            _Pragma("unroll")                                                      \
            for (int r = 0; r < 2; ++r) {                                          \
                int idx = tid + r * 128;                                           \
                int row = idx >> 2, kc = (idx & 3) * 8;                            \
                *(s8v*)&Wsh[row * 40 + kc] = wh[r];                                \
                *(s8v*)&Wsl[row * 40 + kc] = wl[r];                                \
            }                                                                      \
        }

    LOADC3(0);
    STASH3();
    __syncthreads();

    for (int k0 = 0; k0 < K; k0 += 32) {
        bool last = (k0 + 32 >= K);
        if (!last) LOADC3(k0 + 32);

        s8v ah[4], al[4], bh[4], bl[4];
        #pragma unroll
        for (int mt = 0; mt < 4; ++mt) {
            int rowm = wave * 64 + mt * 16 + ln;
            ah[mt] = *(const s8v*)&Xh[rowm * 40 + q * 8];
            al[mt] = *(const s8v*)&Xl[rowm * 40 + q * 8];
        }
        #pragma unroll
        for (int nt = 0; nt < 4; ++nt) {
            int rown = nt * 16 + ln;
            bh[nt] = *(const s8v*)&Wsh[rown * 40 + q * 8];
            bl[nt] = *(const s8v*)&Wsl[rown * 40 + q * 8];
        }
        #pragma unroll
        for (int mt = 0; mt < 4; ++mt)
            #pragma unroll
            for (int nt = 0; nt < 4; ++nt) {
                acc[mt][nt] = __builtin_amdgcn_mfma_f32_16x16x32_bf16(ah[mt], bh[nt], acc[mt][nt], 0, 0, 0);
                acc[mt][nt] = __builtin_amdgcn_mfma_f32_16x16x32_bf16(ah[mt], bl[nt], acc[mt][nt], 0, 0, 0);
                acc[mt][nt] = __builtin_amdgcn_mfma_f32_16x16x32_bf16(al[mt], bh[nt], acc[mt][nt], 0, 0, 0);
            }

        __syncthreads();
        if (!last) {
            STASH3();
            __syncthreads();
        }
    }

    #pragma unroll
    for (int nt = 0; nt < 4; ++nt) {
        int n = n0 + nt * 16 + ln;
        #pragma unroll
        for (int mt = 0; mt < 4; ++mt) {
            int mbase = m0 + wave * 64 + mt * 16 + q * 4;
            #pragma unroll
            for (int r = 0; r < 4; ++r) {
                int m = mbase + r;
                float v = acc[mt][nt][r];
                if (mode & 16) v *= (float)maskMul[(size_t)m * N + n];
                if (mode & 2)  v = fmaxf(v, 0.0f);
                if (mode & 4)  C[(size_t)m * ldc + n] = v;
            }
        }
    }
}

// ---------- zng: bf16 MFMA Jacobian chain, 2 elems/block, 1024 threads ----------
// R11 body; launch bounds relaxed to let the compiler use up to 128 VGPRs
// (R11's (1024,1) clamped to 64 -> 1GB scratch spill). 4 waves/SIMD TLP.
__global__ __launch_bounds__(1024) void zng_kernel(
    const unsigned short* __restrict__ whbf,   // [2][512][512] bf16 (layers 1,2)
    const unsigned short* __restrict__ woutbf, // [64][512] bf16
    const unsigned short* __restrict__ G0tb,   // [64][512] bf16 (G0 transposed)
    const unsigned char* __restrict__ mz1,
    const unsigned char* __restrict__ mz2,
    const unsigned char* __restrict__ mz3,
    float* __restrict__ out)                   // (4096,192), writes cols 128..191
{
    __shared__ __align__(16) unsigned short Rt[2][64 * 512]; // swizzled, no pad
    __shared__ unsigned char m2s[2][512];
    __shared__ unsigned char m3s[2][512];

    const int b0  = blockIdx.x * 2;
    const int tid = threadIdx.x;

    {
        int bb = tid >> 9, k = tid & 511;
        m2s[bb][k] = mz2[(size_t)(b0 + bb) * 512 + k];
        m3s[bb][k] = mz3[(size_t)(b0 + bb) * 512 + k];
    }
    // Phase A: Rt[bb][n][swz(ch)] = bf16(G0t[n][ch*8..]) * D1_bb
    #pragma unroll 4
    for (int i = 0; i < 8; ++i) {
        int c = i * 1024 + tid;            // 0..8191
        int bb = c >> 12, rem = c & 4095;
        int n = rem >> 6, ch = rem & 63;
        int k = ch * 8;
        s8v g = *(const s8v*)(G0tb + n * 512 + k);
        const unsigned char* mm = mz1 + (size_t)(b0 + bb) * 512 + k;
        unsigned int mlo = *(const unsigned int*)(mm);
        unsigned int mhi = *(const unsigned int*)(mm + 4);
        s8v r;
        #pragma unroll
        for (int j = 0; j < 4; ++j) r[j] = ((mlo >> (8 * j)) & 1) ? g[j] : (short)0;
        #pragma unroll
        for (int j = 0; j < 4; ++j) r[4 + j] = ((mhi >> (8 * j)) & 1) ? g[4 + j] : (short)0;
        *(s8v*)(&Rt[bb][n * 512 + ((ch ^ (n & 7)) << 3)]) = r;
    }
    __syncthreads();

    const int lane = tid & 63, wave = tid >> 6;   // wave 0..15
    const int q = lane >> 4, ln = lane & 15;
    const int ln7 = ln & 7;
    const int w8 = wave & 7;                      // m-group
    const int nh = wave >> 3;                     // n-half (0/1)

    // stages: Out_b = Wh[s+1] @ R_b ; R_b <- (D[s+2] (.) Out_b)^T
    for (int s = 0; s < 2; ++s) {
        const unsigned short* A = whbf + (size_t)s * 262144;
        f4v acc[2][4][2];                         // [bb][mt][nt] : 64 VGPRs
        #pragma unroll
        for (int bb = 0; bb < 2; ++bb)
            #pragma unroll
            for (int mt = 0; mt < 4; ++mt)
                #pragma unroll
                for (int nt = 0; nt < 2; ++nt)
                    acc[bb][mt][nt] = (f4v)(0.0f);

        for (int ks = 0; ks < 16; ++ks) {
            int kA = ks * 32 + q * 8;
            s8v af[4];
            #pragma unroll
            for (int mt = 0; mt < 4; ++mt)
                af[mt] = *(const s8v*)(A + (size_t)(w8 * 64 + mt * 16 + ln) * 512 + kA);

            int cB = (ks * 4 + q) ^ ln7;          // swizzled chunk index
            s8v bfr[2][2];
            #pragma unroll
            for (int bb = 0; bb < 2; ++bb)
                #pragma unroll
                for (int nt = 0; nt < 2; ++nt)
                    bfr[bb][nt] = *(const s8v*)(&Rt[bb][(nh * 32 + nt * 16 + ln) * 512 + (cB << 3)]);

            #pragma unroll
            for (int mt = 0; mt < 4; ++mt)
                #pragma unroll
                for (int nt = 0; nt < 2; ++nt) {
                    acc[0][mt][nt] = __builtin_amdgcn_mfma_f32_16x16x32_bf16(af[mt], bfr[0][nt], acc[0][mt][nt], 0, 0, 0);
                    acc[1][mt][nt] = __builtin_amdgcn_mfma_f32_16x16x32_bf16(af[mt], bfr[1][nt], acc[1][mt][nt], 0, 0, 0);
                }
        }
        __syncthreads();   // all reads of old Rt done

        const unsigned char (*msk)[512] = (s == 0) ? m2s : m3s;
        #pragma unroll
        for (int bb = 0; bb < 2; ++bb)
            #pragma unroll
            for (int mt = 0; mt < 4; ++mt) {
                int m0 = w8 * 64 + mt * 16 + q * 4;      // k-position in new R
                int cw = (w8 * 8 + mt * 2 + (q >> 1));   // chunk of m0
                int wo = (q & 1) * 4;                    // short offset in chunk
                uchar4 mv = *(const uchar4*)&msk[bb][m0];
                unsigned char mb[4] = {mv.x, mv.y, mv.z, mv.w};
                #pragma unroll
                for (int nt = 0; nt < 2; ++nt) {
                    int n = nh * 32 + nt * 16 + ln;
                    s4v pk;
                    #pragma unroll
                    for (int r = 0; r < 4; ++r) {
                        float v = mb[r] ? acc[bb][mt][nt][r] : 0.0f;
                        pk[r] = (short)f2bf(v);
                    }
                    *(s4v*)(&Rt[bb][n * 512 + ((cw ^ ln7) << 3) + wo]) = pk;
                }
            }
        __syncthreads();
    }

    // final: g_b = Wout @ R3_b (64x64); zng[m] = ||g_b[m,:]|| — waves 0..7
    if (wave < 8) {
        const int bb = wave >> 2, w4 = wave & 3;
        f4v acc3[4];
        #pragma unroll
        for (int nt = 0; nt < 4; ++nt) acc3[nt] = (f4v)(0.0f);
        for (int ks = 0; ks < 16; ++ks) {
            int kA = ks * 32 + q * 8;
            int cB = (ks * 4 + q) ^ ln7;
            s8v af = *(const s8v*)(woutbf + (size_t)(w4 * 16 + ln) * 512 + kA);
            #pragma unroll
            for (int nt = 0; nt < 4; ++nt) {
                s8v bfr = *(const s8v*)(&Rt[bb][(nt * 16 + ln) * 512 + (cB << 3)]);
                acc3[nt] = __builtin_amdgcn_mfma_f32_16x16x32_bf16(af, bfr, acc3[nt], 0, 0, 0);
            }
        }
        float ss[4];
        #pragma unroll
        for (int r = 0; r < 4; ++r) {
            float s = 0.f;
            #pragma unroll
            for (int nt = 0; nt < 4; ++nt) { float v = acc3[nt][r]; s = fmaf(v, v, s); }
            ss[r] = s;
        }
        #pragma unroll
        for (int off = 1; off < 16; off <<= 1)
            #pragma unroll
            for (int r = 0; r < 4; ++r)
                ss[r] += __shfl_xor(ss[r], off, 64);
        if (ln == 0) {
            #pragma unroll
            for (int r = 0; r < 4; ++r)
                out[(size_t)(b0 + bb) * 192 + 128 + w4 * 16 + q * 4 + r] = sqrtf(ss[r]);
        }
    }
}

// ---------- host ----------
extern "C" void kernel_launch(void* const* d_in, const int* in_sizes, int n_in,
                              void* d_out, int out_size, void* d_ws, size_t ws_size,
                              hipStream_t stream) {
    const float* x    = (const float*)d_in[0];
    const float* Win  = (const float*)d_in[1];
    const float* bin  = (const float*)d_in[2];
    const float* Wh   = (const float*)d_in[3];
    const float* bh   = (const float*)d_in[4];
    const float* Wout = (const float*)d_in[5];
    const float* bout = (const float*)d_in[6];
    float* out = (float*)d_out;

    char* ws = (char*)d_ws;
    unsigned short* whi  = (unsigned short*)(ws);                   // 1703936 B
    unsigned short* wlo  = (unsigned short*)(ws + 1703936);         // 1703936 B
    float*          G0   = (float*)(ws + 3407872);                  // 131072 B
    unsigned short* G0tb = (unsigned short*)(ws + 3538944);         // 65536 B
    unsigned char*  masks = (unsigned char*)(ws + 3604480);         // 6 * 2 MB
    unsigned char* mt1 = masks + 0 * 2097152;
    unsigned char* mt2 = masks + 1 * 2097152;
    unsigned char* mt3 = masks + 2 * 2097152;
    unsigned char* mz1 = masks + 3 * 2097152;
    unsigned char* mz2 = masks + 4 * 2097152;
    unsigned char* mz3 = masks + 5 * 2097152;
    float* bufs = (float*)(ws + 3604480 + 12582912);                // 4 x 8 MB
    float* tA = bufs + 0 * 2097152;
    float* tB = bufs + 1 * 2097152;
    float* zA = bufs + 2 * 2097152;
    float* zB = bufs + 3 * 2097152;

    // hi/lo plane offsets (elems): [Win@0 | Wh0@32768 | Wh1@294912 | Wh2@557056 | Wout@819200]
    const unsigned short* WinH  = whi,          *WinL  = wlo;
    const unsigned short* Wh0H  = whi + 32768,  *Wh0L  = wlo + 32768;
    const unsigned short* Wh1H  = whi + 294912, *Wh1L  = wlo + 294912;
    const unsigned short* Wh2H  = whi + 557056, *Wh2L  = wlo + 557056;
    const unsigned short* WoutH = whi + 819200;

    const float* Wh0 = Wh;
    const float* Wh1 = Wh + 262144;
    const float* Wh2 = Wh + 524288;
    const float* bh0 = bh, *bh1 = bh + 512, *bh2 = bh + 1024;

    conv_split<<<dim3(3328), dim3(256), 0, stream>>>(Win, Wh, Wout, whi, wlo);
    g0_kernel<<<dim3(512), dim3(64), 0, stream>>>(Wh0, Win, G0, G0tb);

    auto gdual = [&](const float* X0, const float* X1, int ldx,
                     const float* W, const unsigned short* WH, const unsigned short* WL, int ldw,
                     const float* bias, float* C0, float* C1, int ldc,
                     unsigned char* mo0, unsigned char* mo1,
                     const unsigned char* mm0, const unsigned char* mm1,
                     int K, int N, int mode) {
        dim3 g(4096 / 128, N / 64, 2);
        gemm_dual<<<g, dim3(256), 0, stream>>>(X0, X1, ldx, W, ldw, WH, WL, bias,
                                               C0, C1, ldc, mo0, mo1, mm0, mm1, K, N, mode);
    };
    auto gemm1 = [&](const float* X, int ldx, const float* W, int ldw, const float* bias,
                     float* C, int ldc, unsigned char* mo, const unsigned char* mm,
                     int K, int N, int mode) {
        dim3 g(4096 / 128, N / 64, 1);
        gemm_nt<<<g, dim3(256), 0, stream>>>(X, ldx, W, ldw, bias, C, ldc, mo, mm, K, N, mode);
    };
    auto g3 = [&](const float* X, int ldx,
                  const unsigned short* WH, const unsigned short* WL, int ldw,
                  float* C, int ldc, const unsigned char* mm, int K, int N, int mode) {
        dim3 g(4096 / 128, N / 64, 1);
        gemm3<<<g, dim3(128), 0, stream>>>(X, ldx, WH, WL, ldw, C, ldc, mm, K, N, mode);
    };

    // ---- fused forward + delta chain (t fp32 ; z split-bf16 MFMA) ----
    gdual(x, x + 128, 192, Win, WinH, WinL, 64, bin, tA, zA, 512, 0, 0, 0, 0, 64, 512, 1 | 4);        // h0
    gdual(tA, zA, 512, Wh0, Wh0H, Wh0L, 512, bh0,   tB, zB, 512, 0, 0, 0, 0, 512, 512, 1 | 2 | 4);    // h1
    gdual(tB, zB, 512, Wh0, Wh0H, Wh0L, 512, bh0,   0, 0, 0, mt1, mz1, 0, 0, 512, 512, 1 | 8);        // delta1
    gdual(tB, zB, 512, Wh1, Wh1H, Wh1L, 512, bh1,   tA, zA, 512, 0, 0, 0, 0, 512, 512, 1 | 2 | 4);    // h2
    gdual(tA, zA, 512, Wh1, Wh1H, Wh1L, 512, bh1,   0, 0, 0, mt2, mz2, 0, 0, 512, 512, 1 | 8);        // delta2
    gdual(tA, zA, 512, Wh2, Wh2H, Wh2L, 512, bh2,   tB, zB, 512, 0, 0, 0, 0, 512, 512, 1 | 2 | 4);    // h3
    gdual(tB, zB, 512, Wh2, Wh2H, Wh2L, 512, bh2,   0, 0, 0, mt3, mz3, 0, 0, 512, 512, 1 | 8);        // delta3

    // ---- zng (z-branch Jacobian row norms), 2 elems/block, 1024 threads ----
    zng_kernel<<<dim3(2048), dim3(1024), 0, stream>>>(Wh1H, WoutH, G0tb, mz1, mz2, mz3, out);

    // ---- h_out (t-branch forward output) — fp32 ----
    gemm1(tB, 512, Wout, 512, bout, out, 192, 0, 0, 512, 64, 1 | 4);                                  // cols 0..63

    // ---- h_dot chain: V = D (.) (W v) ----
    gemm1(x + 64, 192, G0, 64, 0, tA, 512, 0, mt1, 64, 512, 4 | 16);                                  // V1 (fp32)
    g3(tA, 512, Wh1H, Wh1L, 512, zA, 512, mt2, 512, 512, 4 | 16);                                     // V2 (split-bf16)
    g3(zA, 512, Wh2H, Wh2L, 512, zB, 512, mt3, 512, 512, 4 | 16);                                     // V3 (split-bf16)
    gemm1(zB, 512, Wout, 512, 0, out + 64, 192, 0, 0, 512, 64, 4);                                    // h_dot (fp32)
}

// Round 13
// 837.427 us; speedup vs baseline: 1.3918x; 1.3889x over previous
//
#include <hip/hip_runtime.h>
#include <math.h>

typedef __attribute__((ext_vector_type(8))) short s8v;   // 8 x bf16
typedef __attribute__((ext_vector_type(4))) short s4v;   // 4 x bf16
typedef __attribute__((ext_vector_type(4))) float f4v;   // 4 x f32

static __device__ __forceinline__ unsigned short f2bf(float f) {
    union { float f; unsigned int u; } v; v.f = f;
    unsigned int r = v.u + 0x7fffu + ((v.u >> 16) & 1u);   // RNE
    return (unsigned short)(r >> 16);
}
static __device__ __forceinline__ float bf2f(unsigned short h) {
    union { unsigned int u; float f; } t; t.u = ((unsigned int)h) << 16;
    return t.f;
}

// ---------- split all weights to bf16 hi/lo planes ----------
// layout: [Win(32768) | Wh0 | Wh1 | Wh2 (262144 each) | Wout(32768)] = 851968
__global__ void conv_split(const float* __restrict__ Win, const float* __restrict__ Wh,
                           const float* __restrict__ Wout,
                           unsigned short* __restrict__ whi, unsigned short* __restrict__ wlo) {
    int i = blockIdx.x * 256 + threadIdx.x;
    if (i >= 851968) return;
    float v;
    if (i < 32768)       v = Win[i];
    else if (i < 819200) v = Wh[i - 32768];
    else                 v = Wout[i - 819200];
    unsigned short h = f2bf(v);
    whi[i] = h;
    wlo[i] = f2bf(v - bf2f(h));
}

// ---------- G0 = Wh0 @ W_in (512x64): hi/lo planes + transposed hi for zng ----------
__global__ void g0_kernel(const float* __restrict__ Wh0, const float* __restrict__ Win,
                          unsigned short* __restrict__ G0hi, unsigned short* __restrict__ G0lo,
                          unsigned short* __restrict__ G0tb) {
    int i = blockIdx.x;      // 0..511
    int j = threadIdx.x;     // 0..63
    float acc = 0.f;
    for (int k = 0; k < 512; ++k)
        acc = fmaf(Wh0[i * 512 + k], Win[k * 64 + j], acc);
    unsigned short h = f2bf(acc);
    G0hi[i * 64 + j] = h;
    G0lo[i * 64 + j] = f2bf(acc - bf2f(h));
    G0tb[j * 512 + i] = h;
}

// ======== dual GEMM, 512 threads (8 waves): z=0 fp32 4x4 micro (t branch,
// sign-critical, K-order identical to R4 lineage => masks bit-identical);
// z=1 split-bf16 MFMA, 8 waves of 32x32 (z branch, flip-tolerant).
__global__ __launch_bounds__(512) void gemm_dual(
    const float* __restrict__ X0, const float* __restrict__ X1, int ldx,
    const float* __restrict__ W, int ldw,
    const unsigned short* __restrict__ Whi, const unsigned short* __restrict__ Wlo,
    const float* __restrict__ bias,
    float* __restrict__ C0, float* __restrict__ C1, int ldc,
    unsigned char* __restrict__ mo0, unsigned char* __restrict__ mo1,
    const unsigned char* __restrict__ mm0, const unsigned char* __restrict__ mm1,
    int K, int N, int mode)
{
    __shared__ __align__(16) unsigned char lds[30720];
    const int tid = threadIdx.x;
    const int m0 = blockIdx.x * 128;
    const int n0 = blockIdx.y * 64;

    if (blockIdx.z == 0) {
        // ---------------- fp32 vector path, 4x4 micro ----------------
        const float* __restrict__ X = X0;
        float* __restrict__ C = C0;
        unsigned char* __restrict__ maskOut = mo0;
        const unsigned char* __restrict__ maskMul = mm0;
        float (*Xs)[132] = (float(*)[132])lds;                 // 16896 B
        float (*Ws)[68]  = (float(*)[68])(lds + 16896);        // 8704 B
        const int tx = tid & 15, ty = tid >> 4;                // ty 0..31
        float acc[4][4] = {};
        float4 xr[2], wr;

        #define LOADF(k0)                                                            \
            {                                                                        \
                _Pragma("unroll")                                                    \
                for (int r = 0; r < 2; ++r) {                                        \
                    int idx = tid + r * 512;                                         \
                    int row = idx >> 3, kq = (idx & 7) * 4;                          \
                    xr[r] = *(const float4*)(X + (size_t)(m0 + row) * ldx + (k0) + kq); \
                }                                                                    \
                {                                                                    \
                    int row = tid >> 3, kq = (tid & 7) * 4;                          \
                    wr = *(const float4*)(W + (size_t)(n0 + row) * ldw + (k0) + kq); \
                }                                                                    \
            }
        #define STASHF()                                                             \
            {                                                                        \
                _Pragma("unroll")                                                    \
                for (int r = 0; r < 2; ++r) {                                        \
                    int idx = tid + r * 512;                                         \
                    int row = idx >> 3, kq = (idx & 7) * 4;                          \
                    Xs[kq + 0][row] = xr[r].x; Xs[kq + 1][row] = xr[r].y;            \
                    Xs[kq + 2][row] = xr[r].z; Xs[kq + 3][row] = xr[r].w;            \
                }                                                                    \
                {                                                                    \
                    int row = tid >> 3, kq = (tid & 7) * 4;                          \
                    Ws[kq + 0][row] = wr.x; Ws[kq + 1][row] = wr.y;                  \
                    Ws[kq + 2][row] = wr.z; Ws[kq + 3][row] = wr.w;                  \
                }                                                                    \
            }

        LOADF(0);
        STASHF();
        __syncthreads();

        for (int k0 = 0; k0 < K; k0 += 32) {
            bool last = (k0 + 32 >= K);
            if (!last) LOADF(k0 + 32);
            #pragma unroll
            for (int kk = 0; kk < 32; ++kk) {
                float4 a0 = *(const float4*)&Xs[kk][ty * 4];
                float4 b0 = *(const float4*)&Ws[kk][tx * 4];
                float av[4] = {a0.x, a0.y, a0.z, a0.w};
                float bv[4] = {b0.x, b0.y, b0.z, b0.w};
                #pragma unroll
                for (int i = 0; i < 4; ++i)
                    #pragma unroll
                    for (int j = 0; j < 4; ++j)
                        acc[i][j] = fmaf(av[i], bv[j], acc[i][j]);
            }
            __syncthreads();
            if (!last) {
                STASHF();
                __syncthreads();
            }
        }

        float4 bb = {0, 0, 0, 0};
        if (mode & 1) bb = *(const float4*)(bias + n0 + tx * 4);
        const int c0 = n0 + tx * 4;
        #pragma unroll
        for (int i = 0; i < 4; ++i) {
            int r = m0 + ty * 4 + i;
            float v[4];
            #pragma unroll
            for (int j = 0; j < 4; ++j) {
                v[j] = acc[i][j];
                if (mode & 1) v[j] += ((const float*)&bb)[j];
            }
            if (mode & 8) {
                uchar4 mo;
                mo.x = v[0] > 0.0f; mo.y = v[1] > 0.0f; mo.z = v[2] > 0.0f; mo.w = v[3] > 0.0f;
                *(uchar4*)&maskOut[(size_t)r * N + c0] = mo;
            }
            if (mode & 16) {
                uchar4 mm = *(const uchar4*)&maskMul[(size_t)r * N + c0];
                v[0] *= mm.x; v[1] *= mm.y; v[2] *= mm.z; v[3] *= mm.w;
            }
            if (mode & 2) {
                #pragma unroll
                for (int j = 0; j < 4; ++j) v[j] = fmaxf(v[j], 0.0f);
            }
            if (mode & 4) {
                float4 st = {v[0], v[1], v[2], v[3]};
                *(float4*)(C + (size_t)r * ldc + c0) = st;
            }
        }
    } else {
        // ---------------- split-bf16 MFMA path, 8 waves of 32x32 ----------------
        const float* __restrict__ X = X1;
        float* __restrict__ C = C1;
        unsigned char* __restrict__ maskOut = mo1;
        const unsigned char* __restrict__ maskMul = mm1;
        unsigned short* Xh  = (unsigned short*)lds;            // 128*40 = 10240 B
        unsigned short* Xl  = (unsigned short*)(lds + 10240);  // 10240 B
        unsigned short* Wsh = (unsigned short*)(lds + 20480);  // 5120 B
        unsigned short* Wsl = (unsigned short*)(lds + 25600);  // 5120 B

        const int wave = tid >> 6, lane = tid & 63;
        const int q = lane >> 4, ln = lane & 15;
        const int wm = (wave & 3) * 32;      // m-offset (0..96)
        const int wn = (wave >> 2) * 32;     // n-offset (0/32)

        f4v acc[2][2];
        #pragma unroll
        for (int mt = 0; mt < 2; ++mt)
            #pragma unroll
            for (int nt = 0; nt < 2; ++nt)
                acc[mt][nt] = (f4v)(0.0f);

        float4 xr[2];
        s8v wh, wl;
        const bool wload = (tid < 256);

        #define LOADD(k0)                                                              \
            {                                                                          \
                _Pragma("unroll")                                                      \
                for (int r = 0; r < 2; ++r) {                                          \
                    int idx = tid + r * 512;                                           \
                    int row = idx >> 3, kq = (idx & 7) * 4;                            \
                    xr[r] = *(const float4*)(X + (size_t)(m0 + row) * ldx + (k0) + kq); \
                }                                                                      \
                if (wload) {                                                           \
                    int row = tid >> 2, kc = (tid & 3) * 8;                            \
                    wh = *(const s8v*)(Whi + (size_t)(n0 + row) * ldw + (k0) + kc);    \
                    wl = *(const s8v*)(Wlo + (size_t)(n0 + row) * ldw + (k0) + kc);    \
                }                                                                      \
            }
        #define STASHD()                                                               \
            {                                                                          \
                _Pragma("unroll")                                                      \
                for (int r = 0; r < 2; ++r) {                                          \
                    int idx = tid + r * 512;                                           \
                    int row = idx >> 3, kq = (idx & 7) * 4;                            \
                    float a[4] = {xr[r].x, xr[r].y, xr[r].z, xr[r].w};                 \
                    s4v hv, lv;                                                        \
                    _Pragma("unroll")                                                  \
                    for (int j = 0; j < 4; ++j) {                                      \
                        unsigned short h = f2bf(a[j]);                                 \
                        hv[j] = (short)h;                                              \
                        lv[j] = (short)f2bf(a[j] - bf2f(h));                           \
                    }                                                                  \
                    *(s4v*)&Xh[row * 40 + kq] = hv;                                    \
                    *(s4v*)&Xl[row * 40 + kq] = lv;                                    \
                }                                                                      \
                if (wload) {                                                           \
                    int row = tid >> 2, kc = (tid & 3) * 8;                            \
                    *(s8v*)&Wsh[row * 40 + kc] = wh;                                   \
                    *(s8v*)&Wsl[row * 40 + kc] = wl;                                   \
                }                                                                      \
            }

        LOADD(0);
        STASHD();
        __syncthreads();

        for (int k0 = 0; k0 < K; k0 += 32) {
            bool last = (k0 + 32 >= K);
            if (!last) LOADD(k0 + 32);

            s8v ah[2], al[2], bh[2], bl[2];
            #pragma unroll
            for (int mt = 0; mt < 2; ++mt) {
                int rowm = wm + mt * 16 + ln;
                ah[mt] = *(const s8v*)&Xh[rowm * 40 + q * 8];
                al[mt] = *(const s8v*)&Xl[rowm * 40 + q * 8];
            }
            #pragma unroll
            for (int nt = 0; nt < 2; ++nt) {
                int rown = wn + nt * 16 + ln;
                bh[nt] = *(const s8v*)&Wsh[rown * 40 + q * 8];
                bl[nt] = *(const s8v*)&Wsl[rown * 40 + q * 8];
            }
            #pragma unroll
            for (int mt = 0; mt < 2; ++mt)
                #pragma unroll
                for (int nt = 0; nt < 2; ++nt) {
                    acc[mt][nt] = __builtin_amdgcn_mfma_f32_16x16x32_bf16(ah[mt], bh[nt], acc[mt][nt], 0, 0, 0);
                    acc[mt][nt] = __builtin_amdgcn_mfma_f32_16x16x32_bf16(ah[mt], bl[nt], acc[mt][nt], 0, 0, 0);
                    acc[mt][nt] = __builtin_amdgcn_mfma_f32_16x16x32_bf16(al[mt], bh[nt], acc[mt][nt], 0, 0, 0);
                }

            __syncthreads();
            if (!last) {
                STASHD();
                __syncthreads();
            }
        }

        // epilogue: C-layout col=lane&15, row=q*4+r (m89-verified)
        #pragma unroll
        for (int nt = 0; nt < 2; ++nt) {
            int n = n0 + wn + nt * 16 + ln;
            float bv = (mode & 1) ? bias[n] : 0.0f;
            #pragma unroll
            for (int mt = 0; mt < 2; ++mt) {
                int mbase = m0 + wm + mt * 16 + q * 4;
                #pragma unroll
                for (int r = 0; r < 4; ++r) {
                    int m = mbase + r;
                    float v = acc[mt][nt][r] + bv;
                    if (mode & 8)  maskOut[(size_t)m * N + n] = (v > 0.0f) ? 1 : 0;
                    if (mode & 16) v *= (float)maskMul[(size_t)m * N + n];
                    if (mode & 2)  v = fmaxf(v, 0.0f);
                    if (mode & 4)  C[(size_t)m * ldc + n] = v;
                }
            }
        }
    }
}

// ======== fp32 GEMM 128x64 (R4-validated) — t-branch finals ========
__global__ __launch_bounds__(256) void gemm_nt(
    const float* __restrict__ X, int ldx,
    const float* __restrict__ W, int ldw,
    const float* __restrict__ bias,
    float* __restrict__ C, int ldc,
    unsigned char* __restrict__ maskOut,
    const unsigned char* __restrict__ maskMul,
    int K, int N, int mode)
{
    __shared__ float Xs[32][132];
    __shared__ float Ws[32][68];
    const int tid = threadIdx.x;
    const int m0 = blockIdx.x * 128;
    const int n0 = blockIdx.y * 64;
    const int tx = tid & 15, ty = tid >> 4;
    float acc[8][4] = {};
    float4 xr[4], wr[2];

    #define LOADCHUNK(k0)                                                        \
        {                                                                        \
            _Pragma("unroll")                                                    \
            for (int r = 0; r < 4; ++r) {                                        \
                int idx = tid + r * 256;                                         \
                int row = idx >> 3, kq = (idx & 7) * 4;                          \
                xr[r] = *(const float4*)(X + (size_t)(m0 + row) * ldx + (k0) + kq); \
            }                                                                    \
            _Pragma("unroll")                                                    \
            for (int r = 0; r < 2; ++r) {                                        \
                int idx = tid + r * 256;                                         \
                int row = idx >> 3, kq = (idx & 7) * 4;                          \
                wr[r] = *(const float4*)(W + (size_t)(n0 + row) * ldw + (k0) + kq); \
            }                                                                    \
        }
    #define STASH()                                                              \
        {                                                                        \
            _Pragma("unroll")                                                    \
            for (int r = 0; r < 4; ++r) {                                        \
                int idx = tid + r * 256;                                         \
                int row = idx >> 3, kq = (idx & 7) * 4;                          \
                Xs[kq + 0][row] = xr[r].x; Xs[kq + 1][row] = xr[r].y;            \
                Xs[kq + 2][row] = xr[r].z; Xs[kq + 3][row] = xr[r].w;            \
            }                                                                    \
            _Pragma("unroll")                                                    \
            for (int r = 0; r < 2; ++r) {                                        \
                int idx = tid + r * 256;                                         \
                int row = idx >> 3, kq = (idx & 7) * 4;                          \
                Ws[kq + 0][row] = wr[r].x; Ws[kq + 1][row] = wr[r].y;            \
                Ws[kq + 2][row] = wr[r].z; Ws[kq + 3][row] = wr[r].w;            \
            }                                                                    \
        }

    LOADCHUNK(0);
    STASH();
    __syncthreads();

    for (int k0 = 0; k0 < K; k0 += 32) {
        bool last = (k0 + 32 >= K);
        if (!last) LOADCHUNK(k0 + 32);
        #pragma unroll
        for (int kk = 0; kk < 32; ++kk) {
            float4 a0 = *(const float4*)&Xs[kk][ty * 4];
            float4 a1 = *(const float4*)&Xs[kk][64 + ty * 4];
            float4 b0 = *(const float4*)&Ws[kk][tx * 4];
            float av[8] = {a0.x, a0.y, a0.z, a0.w, a1.x, a1.y, a1.z, a1.w};
            float bv[4] = {b0.x, b0.y, b0.z, b0.w};
            #pragma unroll
            for (int i = 0; i < 8; ++i)
                #pragma unroll
                for (int j = 0; j < 4; ++j)
                    acc[i][j] = fmaf(av[i], bv[j], acc[i][j]);
        }
        __syncthreads();
        if (!last) {
            STASH();
            __syncthreads();
        }
    }

    float4 bb = {0, 0, 0, 0};
    if (mode & 1) bb = *(const float4*)(bias + n0 + tx * 4);
    const int c0 = n0 + tx * 4;
    #pragma unroll
    for (int i = 0; i < 8; ++i) {
        int r = m0 + ((i < 4) ? (ty * 4 + i) : (64 + ty * 4 + (i - 4)));
        float v[4];
        #pragma unroll
        for (int j = 0; j < 4; ++j) {
            v[j] = acc[i][j];
            if (mode & 1) v[j] += ((const float*)&bb)[j];
        }
        if (mode & 8) {
            uchar4 mo;
            mo.x = v[0] > 0.0f; mo.y = v[1] > 0.0f; mo.z = v[2] > 0.0f; mo.w = v[3] > 0.0f;
            *(uchar4*)&maskOut[(size_t)r * N + c0] = mo;
        }
        if (mode & 16) {
            uchar4 mm = *(const uchar4*)&maskMul[(size_t)r * N + c0];
            v[0] *= mm.x; v[1] *= mm.y; v[2] *= mm.z; v[3] *= mm.w;
        }
        if (mode & 2) {
            #pragma unroll
            for (int j = 0; j < 4; ++j) v[j] = fmaxf(v[j], 0.0f);
        }
        if (mode & 4) {
            float4 st = {v[0], v[1], v[2], v[3]};
            *(float4*)(C + (size_t)r * ldc + c0) = st;
        }
    }
}

// ======== split-bf16 MFMA GEMM (R9-validated) — V1,V2,V3 ========
__global__ __launch_bounds__(128) void gemm3(
    const float* __restrict__ X, int ldx,
    const unsigned short* __restrict__ Whi, const unsigned short* __restrict__ Wlo, int ldw,
    float* __restrict__ C, int ldc,
    const unsigned char* __restrict__ maskMul,
    int K, int N, int mode)
{
    __shared__ __align__(16) unsigned short Xh[128 * 40];
    __shared__ __align__(16) unsigned short Xl[128 * 40];
    __shared__ __align__(16) unsigned short Wsh[64 * 40];
    __shared__ __align__(16) unsigned short Wsl[64 * 40];

    const int tid = threadIdx.x;
    const int m0 = blockIdx.x * 128;
    const int n0 = blockIdx.y * 64;
    const int wave = tid >> 6, lane = tid & 63;
    const int q = lane >> 4, ln = lane & 15;

    f4v acc[4][4];
    #pragma unroll
    for (int mt = 0; mt < 4; ++mt)
        #pragma unroll
        for (int nt = 0; nt < 4; ++nt)
            acc[mt][nt] = (f4v)(0.0f);

    float4 xr[8];
    s8v wh[2], wl[2];

    #define LOADC3(k0)                                                             \
        {                                                                          \
            _Pragma("unroll")                                                      \
            for (int r = 0; r < 8; ++r) {                                          \
                int idx = tid + r * 128;                                           \
                int row = idx >> 3, kq = (idx & 7) * 4;                            \
                xr[r] = *(const float4*)(X + (size_t)(m0 + row) * ldx + (k0) + kq); \
            }                                                                      \
            _Pragma("unroll")                                                      \
            for (int r = 0; r < 2; ++r) {                                          \
                int idx = tid + r * 128;                                           \
                int row = idx >> 2, kc = (idx & 3) * 8;                            \
                wh[r] = *(const s8v*)(Whi + (size_t)(n0 + row) * ldw + (k0) + kc); \
                wl[r] = *(const s8v*)(Wlo + (size_t)(n0 + row) * ldw + (k0) + kc); \
            }                                                                      \
        }
    #define STASH3()                                                               \
        {                                                                          \
            _Pragma("unroll")                                                      \
            for (int r = 0; r < 8; ++r) {                                          \
                int idx = tid + r * 128;                                           \
                int row = idx >> 3, kq = (idx & 7) * 4;                            \
                float a[4] = {xr[r].x, xr[r].y, xr[r].z, xr[r].w};                 \
                s4v hv, lv;                                                        \
                _Pragma("unroll")                                                  \
                for (int j = 0; j < 4; ++j) {                                      \
                    unsigned short h = f2bf(a[j]);                                 \
                    hv[j] = (short)h;                                              \
                    lv[j] = (short)f2bf(a[j] - bf2f(h));                           \
                }                                                                  \
                *(s4v*)&Xh[row * 40 + kq] = hv;                                    \
                *(s4v*)&Xl[row * 40 + kq] = lv;                                    \
            }                                                                      \
            _Pragma("unroll")                                                      \
            for (int r = 0; r < 2; ++r) {                                          \
                int idx = tid + r * 128;                                           \
                int row = idx >> 2, kc = (idx & 3) * 8;                            \
                *(s8v*)&Wsh[row * 40 + kc] = wh[r];                                \
                *(s8v*)&Wsl[row * 40 + kc] = wl[r];                                \
            }                                                                      \
        }

    LOADC3(0);
    STASH3();
    __syncthreads();

    for (int k0 = 0; k0 < K; k0 += 32) {
        bool last = (k0 + 32 >= K);
        if (!last) LOADC3(k0 + 32);

        s8v ah[4], al[4], bh[4], bl[4];
        #pragma unroll
        for (int mt = 0; mt < 4; ++mt) {
            int rowm = wave * 64 + mt * 16 + ln;
            ah[mt] = *(const s8v*)&Xh[rowm * 40 + q * 8];
            al[mt] = *(const s8v*)&Xl[rowm * 40 + q * 8];
        }
        #pragma unroll
        for (int nt = 0; nt < 4; ++nt) {
            int rown = nt * 16 + ln;
            bh[nt] = *(const s8v*)&Wsh[rown * 40 + q * 8];
            bl[nt] = *(const s8v*)&Wsl[rown * 40 + q * 8];
        }
        #pragma unroll
        for (int mt = 0; mt < 4; ++mt)
            #pragma unroll
            for (int nt = 0; nt < 4; ++nt) {
                acc[mt][nt] = __builtin_amdgcn_mfma_f32_16x16x32_bf16(ah[mt], bh[nt], acc[mt][nt], 0, 0, 0);
                acc[mt][nt] = __builtin_amdgcn_mfma_f32_16x16x32_bf16(ah[mt], bl[nt], acc[mt][nt], 0, 0, 0);
                acc[mt][nt] = __builtin_amdgcn_mfma_f32_16x16x32_bf16(al[mt], bh[nt], acc[mt][nt], 0, 0, 0);
            }

        __syncthreads();
        if (!last) {
            STASH3();
            __syncthreads();
        }
    }

    #pragma unroll
    for (int nt = 0; nt < 4; ++nt) {
        int n = n0 + nt * 16 + ln;
        #pragma unroll
        for (int mt = 0; mt < 4; ++mt) {
            int mbase = m0 + wave * 64 + mt * 16 + q * 4;
            #pragma unroll
            for (int r = 0; r < 4; ++r) {
                int m = mbase + r;
                float v = acc[mt][nt][r];
                if (mode & 16) v *= (float)maskMul[(size_t)m * N + n];
                if (mode & 2)  v = fmaxf(v, 0.0f);
                if (mode & 4)  C[(size_t)m * ldc + n] = v;
            }
        }
    }
}

// ---------- zng: bf16 MFMA Jacobian chain, 2 elems/block (R10-validated, byte-exact) ----------
__global__ __launch_bounds__(512, 2) void zng_kernel(
    const unsigned short* __restrict__ whbf,   // [2][512][512] bf16 (layers 1,2)
    const unsigned short* __restrict__ woutbf, // [64][512] bf16
    const unsigned short* __restrict__ G0tb,   // [64][512] bf16 (G0 transposed)
    const unsigned char* __restrict__ mz1,
    const unsigned char* __restrict__ mz2,
    const unsigned char* __restrict__ mz3,
    float* __restrict__ out)                   // (4096,192), writes cols 128..191
{
    __shared__ __align__(16) unsigned short Rt[2][64 * 512]; // swizzled, no pad
    __shared__ unsigned char m2s[2][512];
    __shared__ unsigned char m3s[2][512];

    const int b0  = blockIdx.x * 2;
    const int tid = threadIdx.x;

    for (int i = tid; i < 1024; i += 512) {
        int bb = i >> 9, k = i & 511;
        m2s[bb][k] = mz2[(size_t)(b0 + bb) * 512 + k];
        m3s[bb][k] = mz3[(size_t)(b0 + bb) * 512 + k];
    }
    #pragma unroll 4
    for (int i = 0; i < 16; ++i) {
        int c = i * 512 + tid;             // 0..8191
        int bb = c >> 12, rem = c & 4095;
        int n = rem >> 6, ch = rem & 63;
        int k = ch * 8;
        s8v g = *(const s8v*)(G0tb + n * 512 + k);
        const unsigned char* mm = mz1 + (size_t)(b0 + bb) * 512 + k;
        unsigned int mlo = *(const unsigned int*)(mm);
        unsigned int mhi = *(const unsigned int*)(mm + 4);
        s8v r;
        #pragma unroll
        for (int j = 0; j < 4; ++j) r[j] = ((mlo >> (8 * j)) & 1) ? g[j] : (short)0;
        #pragma unroll
        for (int j = 0; j < 4; ++j) r[4 + j] = ((mhi >> (8 * j)) & 1) ? g[4 + j] : (short)0;
        *(s8v*)(&Rt[bb][n * 512 + ((ch ^ (n & 7)) << 3)]) = r;
    }
    __syncthreads();

    const int lane = tid & 63, wave = tid >> 6;
    const int q = lane >> 4, ln = lane & 15;
    const int ln7 = ln & 7;

    for (int s = 0; s < 2; ++s) {
        const unsigned short* A = whbf + (size_t)s * 262144;
        f4v acc[2][4][4];
        #pragma unroll
        for (int bb = 0; bb < 2; ++bb)
            #pragma unroll
            for (int mt = 0; mt < 4; ++mt)
                #pragma unroll
                for (int nt = 0; nt < 4; ++nt)
                    acc[bb][mt][nt] = (f4v)(0.0f);

        s8v af[4], afn[4];
        #pragma unroll
        for (int mt = 0; mt < 4; ++mt)
            af[mt] = *(const s8v*)(A + (size_t)(wave * 64 + mt * 16 + ln) * 512 + q * 8);

        #pragma unroll 2
        for (int ks = 0; ks < 16; ++ks) {
            int kAn = ((ks + 1) & 15) * 32 + q * 8;      // wraps; redundant last load
            #pragma unroll
            for (int mt = 0; mt < 4; ++mt)
                afn[mt] = *(const s8v*)(A + (size_t)(wave * 64 + mt * 16 + ln) * 512 + kAn);

            int cB = (ks * 4 + q) ^ ln7;                 // swizzled chunk index
            s8v bfr[2][4];
            #pragma unroll
            for (int bb = 0; bb < 2; ++bb)
                #pragma unroll
                for (int nt = 0; nt < 4; ++nt)
                    bfr[bb][nt] = *(const s8v*)(&Rt[bb][(nt * 16 + ln) * 512 + (cB << 3)]);

            #pragma unroll
            for (int mt = 0; mt < 4; ++mt)
                #pragma unroll
                for (int nt = 0; nt < 4; ++nt) {
                    acc[0][mt][nt] = __builtin_amdgcn_mfma_f32_16x16x32_bf16(af[mt], bfr[0][nt], acc[0][mt][nt], 0, 0, 0);
                    acc[1][mt][nt] = __builtin_amdgcn_mfma_f32_16x16x32_bf16(af[mt], bfr[1][nt], acc[1][mt][nt], 0, 0, 0);
                }
            #pragma unroll
            for (int mt = 0; mt < 4; ++mt) af[mt] = afn[mt];
        }
        __syncthreads();

        const unsigned char (*msk)[512] = (s == 0) ? m2s : m3s;
        #pragma unroll
        for (int bb = 0; bb < 2; ++bb)
            #pragma unroll
            for (int mt = 0; mt < 4; ++mt) {
                int m0 = wave * 64 + mt * 16 + q * 4;    // k-position in new R
                int cw = (wave * 8 + mt * 2 + (q >> 1)); // chunk of m0
                int wo = (q & 1) * 4;                    // short offset in chunk
                uchar4 mv = *(const uchar4*)&msk[bb][m0];
                unsigned char mb[4] = {mv.x, mv.y, mv.z, mv.w};
                #pragma unroll
                for (int nt = 0; nt < 4; ++nt) {
                    int n = nt * 16 + ln;
                    s4v pk;
                    #pragma unroll
                    for (int r = 0; r < 4; ++r) {
                        float v = mb[r] ? acc[bb][mt][nt][r] : 0.0f;
                        pk[r] = (short)f2bf(v);
                    }
                    *(s4v*)(&Rt[bb][n * 512 + ((cw ^ ln7) << 3) + wo]) = pk;
                }
            }
        __syncthreads();
    }

    {
        const int bb = wave >> 2, w4 = wave & 3;
        f4v acc3[4];
        #pragma unroll
        for (int nt = 0; nt < 4; ++nt) acc3[nt] = (f4v)(0.0f);
        for (int ks = 0; ks < 16; ++ks) {
            int kA = ks * 32 + q * 8;
            int cB = (ks * 4 + q) ^ ln7;
            s8v af = *(const s8v*)(woutbf + (size_t)(w4 * 16 + ln) * 512 + kA);
            #pragma unroll
            for (int nt = 0; nt < 4; ++nt) {
                s8v bfr = *(const s8v*)(&Rt[bb][(nt * 16 + ln) * 512 + (cB << 3)]);
                acc3[nt] = __builtin_amdgcn_mfma_f32_16x16x32_bf16(af, bfr, acc3[nt], 0, 0, 0);
            }
        }
        float ss[4];
        #pragma unroll
        for (int r = 0; r < 4; ++r) {
            float s = 0.f;
            #pragma unroll
            for (int nt = 0; nt < 4; ++nt) { float v = acc3[nt][r]; s = fmaf(v, v, s); }
            ss[r] = s;
        }
        #pragma unroll
        for (int off = 1; off < 16; off <<= 1)
            #pragma unroll
            for (int r = 0; r < 4; ++r)
                ss[r] += __shfl_xor(ss[r], off, 64);
        if (ln == 0) {
            #pragma unroll
            for (int r = 0; r < 4; ++r)
                out[(size_t)(b0 + bb) * 192 + 128 + w4 * 16 + q * 4 + r] = sqrtf(ss[r]);
        }
    }
}

// ---------- host ----------
extern "C" void kernel_launch(void* const* d_in, const int* in_sizes, int n_in,
                              void* d_out, int out_size, void* d_ws, size_t ws_size,
                              hipStream_t stream) {
    const float* x    = (const float*)d_in[0];
    const float* Win  = (const float*)d_in[1];
    const float* bin  = (const float*)d_in[2];
    const float* Wh   = (const float*)d_in[3];
    const float* bh   = (const float*)d_in[4];
    const float* Wout = (const float*)d_in[5];
    const float* bout = (const float*)d_in[6];
    float* out = (float*)d_out;

    char* ws = (char*)d_ws;
    unsigned short* whi  = (unsigned short*)(ws);                   // 1703936 B
    unsigned short* wlo  = (unsigned short*)(ws + 1703936);         // 1703936 B
    unsigned short* G0hi = (unsigned short*)(ws + 3407872);         // 65536 B
    unsigned short* G0lo = (unsigned short*)(ws + 3473408);         // 65536 B
    unsigned short* G0tb = (unsigned short*)(ws + 3538944);         // 65536 B
    unsigned char*  masks = (unsigned char*)(ws + 3604480);         // 6 * 2 MB
    unsigned char* mt1 = masks + 0 * 2097152;
    unsigned char* mt2 = masks + 1 * 2097152;
    unsigned char* mt3 = masks + 2 * 2097152;
    unsigned char* mz1 = masks + 3 * 2097152;
    unsigned char* mz2 = masks + 4 * 2097152;
    unsigned char* mz3 = masks + 5 * 2097152;
    float* bufs = (float*)(ws + 3604480 + 12582912);                // 4 x 8 MB
    float* tA = bufs + 0 * 2097152;
    float* tB = bufs + 1 * 2097152;
    float* zA = bufs + 2 * 2097152;
    float* zB = bufs + 3 * 2097152;

    // hi/lo plane offsets (elems): [Win@0 | Wh0@32768 | Wh1@294912 | Wh2@557056 | Wout@819200]
    const unsigned short* WinH  = whi,          *WinL  = wlo;
    const unsigned short* Wh0H  = whi + 32768,  *Wh0L  = wlo + 32768;
    const unsigned short* Wh1H  = whi + 294912, *Wh1L  = wlo + 294912;
    const unsigned short* Wh2H  = whi + 557056, *Wh2L  = wlo + 557056;
    const unsigned short* WoutH = whi + 819200;

    const float* Wh0 = Wh;
    const float* Wh1 = Wh + 262144;
    const float* Wh2 = Wh + 524288;
    const float* bh0 = bh, *bh1 = bh + 512, *bh2 = bh + 1024;

    conv_split<<<dim3(3328), dim3(256), 0, stream>>>(Win, Wh, Wout, whi, wlo);
    g0_kernel<<<dim3(512), dim3(64), 0, stream>>>(Wh0, Win, G0hi, G0lo, G0tb);

    auto gdual = [&](const float* X0, const float* X1, int ldx,
                     const float* W, const unsigned short* WH, const unsigned short* WL, int ldw,
                     const float* bias, float* C0, float* C1, int ldc,
                     unsigned char* mo0, unsigned char* mo1,
                     const unsigned char* mm0, const unsigned char* mm1,
                     int K, int N, int mode) {
        dim3 g(4096 / 128, N / 64, 2);
        gemm_dual<<<g, dim3(512), 0, stream>>>(X0, X1, ldx, W, ldw, WH, WL, bias,
                                               C0, C1, ldc, mo0, mo1, mm0, mm1, K, N, mode);
    };
    auto gemm1 = [&](const float* X, int ldx, const float* W, int ldw, const float* bias,
                     float* C, int ldc, unsigned char* mo, const unsigned char* mm,
                     int K, int N, int mode) {
        dim3 g(4096 / 128, N / 64, 1);
        gemm_nt<<<g, dim3(256), 0, stream>>>(X, ldx, W, ldw, bias, C, ldc, mo, mm, K, N, mode);
    };
    auto g3 = [&](const float* X, int ldx,
                  const unsigned short* WH, const unsigned short* WL, int ldw,
                  float* C, int ldc, const unsigned char* mm, int K, int N, int mode) {
        dim3 g(4096 / 128, N / 64, 1);
        gemm3<<<g, dim3(128), 0, stream>>>(X, ldx, WH, WL, ldw, C, ldc, mm, K, N, mode);
    };

    // ---- fused forward + delta chain (t fp32 ; z split-bf16 MFMA) ----
    gdual(x, x + 128, 192, Win, WinH, WinL, 64, bin, tA, zA, 512, 0, 0, 0, 0, 64, 512, 1 | 4);        // h0
    gdual(tA, zA, 512, Wh0, Wh0H, Wh0L, 512, bh0,   tB, zB, 512, 0, 0, 0, 0, 512, 512, 1 | 2 | 4);    // h1
    gdual(tB, zB, 512, Wh0, Wh0H, Wh0L, 512, bh0,   0, 0, 0, mt1, mz1, 0, 0, 512, 512, 1 | 8);        // delta1
    gdual(tB, zB, 512, Wh1, Wh1H, Wh1L, 512, bh1,   tA, zA, 512, 0, 0, 0, 0, 512, 512, 1 | 2 | 4);    // h2
    gdual(tA, zA, 512, Wh1, Wh1H, Wh1L, 512, bh1,   0, 0, 0, mt2, mz2, 0, 0, 512, 512, 1 | 8);        // delta2
    gdual(tA, zA, 512, Wh2, Wh2H, Wh2L, 512, bh2,   tB, zB, 512, 0, 0, 0, 0, 512, 512, 1 | 2 | 4);    // h3
    gdual(tB, zB, 512, Wh2, Wh2H, Wh2L, 512, bh2,   0, 0, 0, mt3, mz3, 0, 0, 512, 512, 1 | 8);        // delta3

    // ---- zng (z-branch Jacobian row norms), 2 elems/block ----
    zng_kernel<<<dim3(2048), dim3(512), 0, stream>>>(Wh1H, WoutH, G0tb, mz1, mz2, mz3, out);

    // ---- h_out (t-branch forward output) — fp32 ----
    gemm1(tB, 512, Wout, 512, bout, out, 192, 0, 0, 512, 64, 1 | 4);                                  // cols 0..63

    // ---- h_dot chain: V = D (.) (W v) ----
    g3(x + 64, 192, G0hi, G0lo, 64, tA, 512, mt1, 64, 512, 4 | 16);                                   // V1 (split-bf16)
    g3(tA, 512, Wh1H, Wh1L, 512, zA, 512, mt2, 512, 512, 4 | 16);                                     // V2 (split-bf16)
    g3(zA, 512, Wh2H, Wh2L, 512, zB, 512, mt3, 512, 512, 4 | 16);                                     // V3 (split-bf16)
    gemm1(zB, 512, Wout, 512, 0, out + 64, 192, 0, 0, 512, 64, 4);                                    // h_dot (fp32)
}

// Round 14
// 829.731 us; speedup vs baseline: 1.4048x; 1.0093x over previous
//
#include <hip/hip_runtime.h>
#include <math.h>

typedef __attribute__((ext_vector_type(8))) short s8v;   // 8 x bf16
typedef __attribute__((ext_vector_type(4))) short s4v;   // 4 x bf16
typedef __attribute__((ext_vector_type(4))) float f4v;   // 4 x f32

static __device__ __forceinline__ unsigned short f2bf(float f) {
    union { float f; unsigned int u; } v; v.f = f;
    unsigned int r = v.u + 0x7fffu + ((v.u >> 16) & 1u);   // RNE
    return (unsigned short)(r >> 16);
}
static __device__ __forceinline__ float bf2f(unsigned short h) {
    union { unsigned int u; float f; } t; t.u = ((unsigned int)h) << 16;
    return t.f;
}

// ---------- split all weights to bf16 hi/lo planes ----------
// layout: [Win(32768) | Wh0 | Wh1 | Wh2 (262144 each) | Wout(32768)] = 851968
__global__ void conv_split(const float* __restrict__ Win, const float* __restrict__ Wh,
                           const float* __restrict__ Wout,
                           unsigned short* __restrict__ whi, unsigned short* __restrict__ wlo) {
    int i = blockIdx.x * 256 + threadIdx.x;
    if (i >= 851968) return;
    float v;
    if (i < 32768)       v = Win[i];
    else if (i < 819200) v = Wh[i - 32768];
    else                 v = Wout[i - 819200];
    unsigned short h = f2bf(v);
    whi[i] = h;
    wlo[i] = f2bf(v - bf2f(h));
}

// ---------- G0 = Wh0 @ W_in (512x64): hi/lo planes + transposed hi for zng ----------
__global__ void g0_kernel(const float* __restrict__ Wh0, const float* __restrict__ Win,
                          unsigned short* __restrict__ G0hi, unsigned short* __restrict__ G0lo,
                          unsigned short* __restrict__ G0tb) {
    int i = blockIdx.x;      // 0..511
    int j = threadIdx.x;     // 0..63
    float acc = 0.f;
    for (int k = 0; k < 512; ++k)
        acc = fmaf(Wh0[i * 512 + k], Win[k * 64 + j], acc);
    unsigned short h = f2bf(acc);
    G0hi[i * 64 + j] = h;
    G0lo[i * 64 + j] = f2bf(acc - bf2f(h));
    G0tb[j * 512 + i] = h;
}

// ======== dual GEMM, 512 threads (R13-validated): z=0 fp32 4x4 micro (t branch);
//          z=1 split-bf16 MFMA, 8 waves of 32x32 (z branch, flip-tolerant).
__global__ __launch_bounds__(512) void gemm_dual(
    const float* __restrict__ X0, const float* __restrict__ X1, int ldx,
    const float* __restrict__ W, int ldw,
    const unsigned short* __restrict__ Whi, const unsigned short* __restrict__ Wlo,
    const float* __restrict__ bias,
    float* __restrict__ C0, float* __restrict__ C1, int ldc,
    unsigned char* __restrict__ mo0, unsigned char* __restrict__ mo1,
    const unsigned char* __restrict__ mm0, const unsigned char* __restrict__ mm1,
    int K, int N, int mode)
{
    __shared__ __align__(16) unsigned char lds[30720];
    const int tid = threadIdx.x;
    const int m0 = blockIdx.x * 128;
    const int n0 = blockIdx.y * 64;

    if (blockIdx.z == 0) {
        // ---------------- fp32 vector path, 4x4 micro ----------------
        const float* __restrict__ X = X0;
        float* __restrict__ C = C0;
        unsigned char* __restrict__ maskOut = mo0;
        const unsigned char* __restrict__ maskMul = mm0;
        float (*Xs)[132] = (float(*)[132])lds;                 // 16896 B
        float (*Ws)[68]  = (float(*)[68])(lds + 16896);        // 8704 B
        const int tx = tid & 15, ty = tid >> 4;                // ty 0..31
        float acc[4][4] = {};
        float4 xr[2], wr;

        #define LOADF(k0)                                                            \
            {                                                                        \
                _Pragma("unroll")                                                    \
                for (int r = 0; r < 2; ++r) {                                        \
                    int idx = tid + r * 512;                                         \
                    int row = idx >> 3, kq = (idx & 7) * 4;                          \
                    xr[r] = *(const float4*)(X + (size_t)(m0 + row) * ldx + (k0) + kq); \
                }                                                                    \
                {                                                                    \
                    int row = tid >> 3, kq = (tid & 7) * 4;                          \
                    wr = *(const float4*)(W + (size_t)(n0 + row) * ldw + (k0) + kq); \
                }                                                                    \
            }
        #define STASHF()                                                             \
            {                                                                        \
                _Pragma("unroll")                                                    \
                for (int r = 0; r < 2; ++r) {                                        \
                    int idx = tid + r * 512;                                         \
                    int row = idx >> 3, kq = (idx & 7) * 4;                          \
                    Xs[kq + 0][row] = xr[r].x; Xs[kq + 1][row] = xr[r].y;            \
                    Xs[kq + 2][row] = xr[r].z; Xs[kq + 3][row] = xr[r].w;            \
                }                                                                    \
                {                                                                    \
                    int row = tid >> 3, kq = (tid & 7) * 4;                          \
                    Ws[kq + 0][row] = wr.x; Ws[kq + 1][row] = wr.y;                  \
                    Ws[kq + 2][row] = wr.z; Ws[kq + 3][row] = wr.w;                  \
                }                                                                    \
            }

        LOADF(0);
        STASHF();
        __syncthreads();

        for (int k0 = 0; k0 < K; k0 += 32) {
            bool last = (k0 + 32 >= K);
            if (!last) LOADF(k0 + 32);
            #pragma unroll
            for (int kk = 0; kk < 32; ++kk) {
                float4 a0 = *(const float4*)&Xs[kk][ty * 4];
                float4 b0 = *(const float4*)&Ws[kk][tx * 4];
                float av[4] = {a0.x, a0.y, a0.z, a0.w};
                float bv[4] = {b0.x, b0.y, b0.z, b0.w};
                #pragma unroll
                for (int i = 0; i < 4; ++i)
                    #pragma unroll
                    for (int j = 0; j < 4; ++j)
                        acc[i][j] = fmaf(av[i], bv[j], acc[i][j]);
            }
            __syncthreads();
            if (!last) {
                STASHF();
                __syncthreads();
            }
        }

        float4 bb = {0, 0, 0, 0};
        if (mode & 1) bb = *(const float4*)(bias + n0 + tx * 4);
        const int c0 = n0 + tx * 4;
        #pragma unroll
        for (int i = 0; i < 4; ++i) {
            int r = m0 + ty * 4 + i;
            float v[4];
            #pragma unroll
            for (int j = 0; j < 4; ++j) {
                v[j] = acc[i][j];
                if (mode & 1) v[j] += ((const float*)&bb)[j];
            }
            if (mode & 8) {
                uchar4 mo;
                mo.x = v[0] > 0.0f; mo.y = v[1] > 0.0f; mo.z = v[2] > 0.0f; mo.w = v[3] > 0.0f;
                *(uchar4*)&maskOut[(size_t)r * N + c0] = mo;
            }
            if (mode & 16) {
                uchar4 mm = *(const uchar4*)&maskMul[(size_t)r * N + c0];
                v[0] *= mm.x; v[1] *= mm.y; v[2] *= mm.z; v[3] *= mm.w;
            }
            if (mode & 2) {
                #pragma unroll
                for (int j = 0; j < 4; ++j) v[j] = fmaxf(v[j], 0.0f);
            }
            if (mode & 4) {
                float4 st = {v[0], v[1], v[2], v[3]};
                *(float4*)(C + (size_t)r * ldc + c0) = st;
            }
        }
    } else {
        // ---------------- split-bf16 MFMA path, 8 waves of 32x32 ----------------
        const float* __restrict__ X = X1;
        float* __restrict__ C = C1;
        unsigned char* __restrict__ maskOut = mo1;
        const unsigned char* __restrict__ maskMul = mm1;
        unsigned short* Xh  = (unsigned short*)lds;            // 128*40 = 10240 B
        unsigned short* Xl  = (unsigned short*)(lds + 10240);  // 10240 B
        unsigned short* Wsh = (unsigned short*)(lds + 20480);  // 5120 B
        unsigned short* Wsl = (unsigned short*)(lds + 25600);  // 5120 B

        const int wave = tid >> 6, lane = tid & 63;
        const int q = lane >> 4, ln = lane & 15;
        const int wm = (wave & 3) * 32;      // m-offset (0..96)
        const int wn = (wave >> 2) * 32;     // n-offset (0/32)

        f4v acc[2][2];
        #pragma unroll
        for (int mt = 0; mt < 2; ++mt)
            #pragma unroll
            for (int nt = 0; nt < 2; ++nt)
                acc[mt][nt] = (f4v)(0.0f);

        float4 xr[2];
        s8v wh, wl;
        const bool wload = (tid < 256);

        #define LOADD(k0)                                                              \
            {                                                                          \
                _Pragma("unroll")                                                      \
                for (int r = 0; r < 2; ++r) {                                          \
                    int idx = tid + r * 512;                                           \
                    int row = idx >> 3, kq = (idx & 7) * 4;                            \
                    xr[r] = *(const float4*)(X + (size_t)(m0 + row) * ldx + (k0) + kq); \
                }                                                                      \
                if (wload) {                                                           \
                    int row = tid >> 2, kc = (tid & 3) * 8;                            \
                    wh = *(const s8v*)(Whi + (size_t)(n0 + row) * ldw + (k0) + kc);    \
                    wl = *(const s8v*)(Wlo + (size_t)(n0 + row) * ldw + (k0) + kc);    \
                }                                                                      \
            }
        #define STASHD()                                                               \
            {                                                                          \
                _Pragma("unroll")                                                      \
                for (int r = 0; r < 2; ++r) {                                          \
                    int idx = tid + r * 512;                                           \
                    int row = idx >> 3, kq = (idx & 7) * 4;                            \
                    float a[4] = {xr[r].x, xr[r].y, xr[r].z, xr[r].w};                 \
                    s4v hv, lv;                                                        \
                    _Pragma("unroll")                                                  \
                    for (int j = 0; j < 4; ++j) {                                      \
                        unsigned short h = f2bf(a[j]);                                 \
                        hv[j] = (short)h;                                              \
                        lv[j] = (short)f2bf(a[j] - bf2f(h));                           \
                    }                                                                  \
                    *(s4v*)&Xh[row * 40 + kq] = hv;                                    \
                    *(s4v*)&Xl[row * 40 + kq] = lv;                                    \
                }                                                                      \
                if (wload) {                                                           \
                    int row = tid >> 2, kc = (tid & 3) * 8;                            \
                    *(s8v*)&Wsh[row * 40 + kc] = wh;                                   \
                    *(s8v*)&Wsl[row * 40 + kc] = wl;                                   \
                }                                                                      \
            }

        LOADD(0);
        STASHD();
        __syncthreads();

        for (int k0 = 0; k0 < K; k0 += 32) {
            bool last = (k0 + 32 >= K);
            if (!last) LOADD(k0 + 32);

            s8v ah[2], al[2], bh[2], bl[2];
            #pragma unroll
            for (int mt = 0; mt < 2; ++mt) {
                int rowm = wm + mt * 16 + ln;
                ah[mt] = *(const s8v*)&Xh[rowm * 40 + q * 8];
                al[mt] = *(const s8v*)&Xl[rowm * 40 + q * 8];
            }
            #pragma unroll
            for (int nt = 0; nt < 2; ++nt) {
                int rown = wn + nt * 16 + ln;
                bh[nt] = *(const s8v*)&Wsh[rown * 40 + q * 8];
                bl[nt] = *(const s8v*)&Wsl[rown * 40 + q * 8];
            }
            #pragma unroll
            for (int mt = 0; mt < 2; ++mt)
                #pragma unroll
                for (int nt = 0; nt < 2; ++nt) {
                    acc[mt][nt] = __builtin_amdgcn_mfma_f32_16x16x32_bf16(ah[mt], bh[nt], acc[mt][nt], 0, 0, 0);
                    acc[mt][nt] = __builtin_amdgcn_mfma_f32_16x16x32_bf16(ah[mt], bl[nt], acc[mt][nt], 0, 0, 0);
                    acc[mt][nt] = __builtin_amdgcn_mfma_f32_16x16x32_bf16(al[mt], bh[nt], acc[mt][nt], 0, 0, 0);
                }

            __syncthreads();
            if (!last) {
                STASHD();
                __syncthreads();
            }
        }

        // epilogue: C-layout col=lane&15, row=q*4+r (m89-verified)
        #pragma unroll
        for (int nt = 0; nt < 2; ++nt) {
            int n = n0 + wn + nt * 16 + ln;
            float bv = (mode & 1) ? bias[n] : 0.0f;
            #pragma unroll
            for (int mt = 0; mt < 2; ++mt) {
                int mbase = m0 + wm + mt * 16 + q * 4;
                #pragma unroll
                for (int r = 0; r < 4; ++r) {
                    int m = mbase + r;
                    float v = acc[mt][nt][r] + bv;
                    if (mode & 8)  maskOut[(size_t)m * N + n] = (v > 0.0f) ? 1 : 0;
                    if (mode & 16) v *= (float)maskMul[(size_t)m * N + n];
                    if (mode & 2)  v = fmaxf(v, 0.0f);
                    if (mode & 4)  C[(size_t)m * ldc + n] = v;
                }
            }
        }
    }
}

// ======== fp32 GEMM 128x64 (R4-validated) — t-branch finals ========
__global__ __launch_bounds__(256) void gemm_nt(
    const float* __restrict__ X, int ldx,
    const float* __restrict__ W, int ldw,
    const float* __restrict__ bias,
    float* __restrict__ C, int ldc,
    unsigned char* __restrict__ maskOut,
    const unsigned char* __restrict__ maskMul,
    int K, int N, int mode)
{
    __shared__ float Xs[32][132];
    __shared__ float Ws[32][68];
    const int tid = threadIdx.x;
    const int m0 = blockIdx.x * 128;
    const int n0 = blockIdx.y * 64;
    const int tx = tid & 15, ty = tid >> 4;
    float acc[8][4] = {};
    float4 xr[4], wr[2];

    #define LOADCHUNK(k0)                                                        \
        {                                                                        \
            _Pragma("unroll")                                                    \
            for (int r = 0; r < 4; ++r) {                                        \
                int idx = tid + r * 256;                                         \
                int row = idx >> 3, kq = (idx & 7) * 4;                          \
                xr[r] = *(const float4*)(X + (size_t)(m0 + row) * ldx + (k0) + kq); \
            }                                                                    \
            _Pragma("unroll")                                                    \
            for (int r = 0; r < 2; ++r) {                                        \
                int idx = tid + r * 256;                                         \
                int row = idx >> 3, kq = (idx & 7) * 4;                          \
                wr[r] = *(const float4*)(W + (size_t)(n0 + row) * ldw + (k0) + kq); \
            }                                                                    \
        }
    #define STASH()                                                              \
        {                                                                        \
            _Pragma("unroll")                                                    \
            for (int r = 0; r < 4; ++r) {                                        \
                int idx = tid + r * 256;                                         \
                int row = idx >> 3, kq = (idx & 7) * 4;                          \
                Xs[kq + 0][row] = xr[r].x; Xs[kq + 1][row] = xr[r].y;            \
                Xs[kq + 2][row] = xr[r].z; Xs[kq + 3][row] = xr[r].w;            \
            }                                                                    \
            _Pragma("unroll")                                                    \
            for (int r = 0; r < 2; ++r) {                                        \
                int idx = tid + r * 256;                                         \
                int row = idx >> 3, kq = (idx & 7) * 4;                          \
                Ws[kq + 0][row] = wr[r].x; Ws[kq + 1][row] = wr[r].y;            \
                Ws[kq + 2][row] = wr[r].z; Ws[kq + 3][row] = wr[r].w;            \
            }                                                                    \
        }

    LOADCHUNK(0);
    STASH();
    __syncthreads();

    for (int k0 = 0; k0 < K; k0 += 32) {
        bool last = (k0 + 32 >= K);
        if (!last) LOADCHUNK(k0 + 32);
        #pragma unroll
        for (int kk = 0; kk < 32; ++kk) {
            float4 a0 = *(const float4*)&Xs[kk][ty * 4];
            float4 a1 = *(const float4*)&Xs[kk][64 + ty * 4];
            float4 b0 = *(const float4*)&Ws[kk][tx * 4];
            float av[8] = {a0.x, a0.y, a0.z, a0.w, a1.x, a1.y, a1.z, a1.w};
            float bv[4] = {b0.x, b0.y, b0.z, b0.w};
            #pragma unroll
            for (int i = 0; i < 8; ++i)
                #pragma unroll
                for (int j = 0; j < 4; ++j)
                    acc[i][j] = fmaf(av[i], bv[j], acc[i][j]);
        }
        __syncthreads();
        if (!last) {
            STASH();
            __syncthreads();
        }
    }

    float4 bb = {0, 0, 0, 0};
    if (mode & 1) bb = *(const float4*)(bias + n0 + tx * 4);
    const int c0 = n0 + tx * 4;
    #pragma unroll
    for (int i = 0; i < 8; ++i) {
        int r = m0 + ((i < 4) ? (ty * 4 + i) : (64 + ty * 4 + (i - 4)));
        float v[4];
        #pragma unroll
        for (int j = 0; j < 4; ++j) {
            v[j] = acc[i][j];
            if (mode & 1) v[j] += ((const float*)&bb)[j];
        }
        if (mode & 8) {
            uchar4 mo;
            mo.x = v[0] > 0.0f; mo.y = v[1] > 0.0f; mo.z = v[2] > 0.0f; mo.w = v[3] > 0.0f;
            *(uchar4*)&maskOut[(size_t)r * N + c0] = mo;
        }
        if (mode & 16) {
            uchar4 mm = *(const uchar4*)&maskMul[(size_t)r * N + c0];
            v[0] *= mm.x; v[1] *= mm.y; v[2] *= mm.z; v[3] *= mm.w;
        }
        if (mode & 2) {
            #pragma unroll
            for (int j = 0; j < 4; ++j) v[j] = fmaxf(v[j], 0.0f);
        }
        if (mode & 4) {
            float4 st = {v[0], v[1], v[2], v[3]};
            *(float4*)(C + (size_t)r * ldc + c0) = st;
        }
    }
}

// ======== split-bf16 MFMA GEMM (R9-validated) — V1,V2,V3 ========
__global__ __launch_bounds__(128) void gemm3(
    const float* __restrict__ X, int ldx,
    const unsigned short* __restrict__ Whi, const unsigned short* __restrict__ Wlo, int ldw,
    float* __restrict__ C, int ldc,
    const unsigned char* __restrict__ maskMul,
    int K, int N, int mode)
{
    __shared__ __align__(16) unsigned short Xh[128 * 40];
    __shared__ __align__(16) unsigned short Xl[128 * 40];
    __shared__ __align__(16) unsigned short Wsh[64 * 40];
    __shared__ __align__(16) unsigned short Wsl[64 * 40];

    const int tid = threadIdx.x;
    const int m0 = blockIdx.x * 128;
    const int n0 = blockIdx.y * 64;
    const int wave = tid >> 6, lane = tid & 63;
    const int q = lane >> 4, ln = lane & 15;

    f4v acc[4][4];
    #pragma unroll
    for (int mt = 0; mt < 4; ++mt)
        #pragma unroll
        for (int nt = 0; nt < 4; ++nt)
            acc[mt][nt] = (f4v)(0.0f);

    float4 xr[8];
    s8v wh[2], wl[2];

    #define LOADC3(k0)                                                             \
        {                                                                          \
            _Pragma("unroll")                                                      \
            for (int r = 0; r < 8; ++r) {                                          \
                int idx = tid + r * 128;                                           \
                int row = idx >> 3, kq = (idx & 7) * 4;                            \
                xr[r] = *(const float4*)(X + (size_t)(m0 + row) * ldx + (k0) + kq); \
            }                                                                      \
            _Pragma("unroll")                                                      \
            for (int r = 0; r < 2; ++r) {                                          \
                int idx = tid + r * 128;                                           \
                int row = idx >> 2, kc = (idx & 3) * 8;                            \
                wh[r] = *(const s8v*)(Whi + (size_t)(n0 + row) * ldw + (k0) + kc); \
                wl[r] = *(const s8v*)(Wlo + (size_t)(n0 + row) * ldw + (k0) + kc); \
            }                                                                      \
        }
    #define STASH3()                                                               \
        {                                                                          \
            _Pragma("unroll")                                                      \
            for (int r = 0; r < 8; ++r) {                                          \
                int idx = tid + r * 128;                                           \
                int row = idx >> 3, kq = (idx & 7) * 4;                            \
                float a[4] = {xr[r].x, xr[r].y, xr[r].z, xr[r].w};                 \
                s4v hv, lv;                                                        \
                _Pragma("unroll")                                                  \
                for (int j = 0; j < 4; ++j) {                                      \
                    unsigned short h = f2bf(a[j]);                                 \
                    hv[j] = (short)h;                                              \
                    lv[j] = (short)f2bf(a[j] - bf2f(h));                           \
                }                                                                  \
                *(s4v*)&Xh[row * 40 + kq] = hv;                                    \
                *(s4v*)&Xl[row * 40 + kq] = lv;                                    \
            }                                                                      \
            _Pragma("unroll")                                                      \
            for (int r = 0; r < 2; ++r) {                                          \
                int idx = tid + r * 128;                                           \
                int row = idx >> 2, kc = (idx & 3) * 8;                            \
                *(s8v*)&Wsh[row * 40 + kc] = wh[r];                                \
                *(s8v*)&Wsl[row * 40 + kc] = wl[r];                                \
            }                                                                      \
        }

    LOADC3(0);
    STASH3();
    __syncthreads();

    for (int k0 = 0; k0 < K; k0 += 32) {
        bool last = (k0 + 32 >= K);
        if (!last) LOADC3(k0 + 32);

        s8v ah[4], al[4], bh[4], bl[4];
        #pragma unroll
        for (int mt = 0; mt < 4; ++mt) {
            int rowm = wave * 64 + mt * 16 + ln;
            ah[mt] = *(const s8v*)&Xh[rowm * 40 + q * 8];
            al[mt] = *(const s8v*)&Xl[rowm * 40 + q * 8];
        }
        #pragma unroll
        for (int nt = 0; nt < 4; ++nt) {
            int rown = nt * 16 + ln;
            bh[nt] = *(const s8v*)&Wsh[rown * 40 + q * 8];
            bl[nt] = *(const s8v*)&Wsl[rown * 40 + q * 8];
        }
        #pragma unroll
        for (int mt = 0; mt < 4; ++mt)
            #pragma unroll
            for (int nt = 0; nt < 4; ++nt) {
                acc[mt][nt] = __builtin_amdgcn_mfma_f32_16x16x32_bf16(ah[mt], bh[nt], acc[mt][nt], 0, 0, 0);
                acc[mt][nt] = __builtin_amdgcn_mfma_f32_16x16x32_bf16(ah[mt], bl[nt], acc[mt][nt], 0, 0, 0);
                acc[mt][nt] = __builtin_amdgcn_mfma_f32_16x16x32_bf16(al[mt], bh[nt], acc[mt][nt], 0, 0, 0);
            }

        __syncthreads();
        if (!last) {
            STASH3();
            __syncthreads();
        }
    }

    #pragma unroll
    for (int nt = 0; nt < 4; ++nt) {
        int n = n0 + nt * 16 + ln;
        #pragma unroll
        for (int mt = 0; mt < 4; ++mt) {
            int mbase = m0 + wave * 64 + mt * 16 + q * 4;
            #pragma unroll
            for (int r = 0; r < 4; ++r) {
                int m = mbase + r;
                float v = acc[mt][nt][r];
                if (mode & 16) v *= (float)maskMul[(size_t)m * N + n];
                if (mode & 2)  v = fmaxf(v, 0.0f);
                if (mode & 4)  C[(size_t)m * ldc + n] = v;
            }
        }
    }
}

// ---------- zng: bf16 MFMA Jacobian chain, 2 elems/block (R10 body + 2-deep A prefetch) ----------
__global__ __launch_bounds__(512, 2) void zng_kernel(
    const unsigned short* __restrict__ whbf,   // [2][512][512] bf16 (layers 1,2)
    const unsigned short* __restrict__ woutbf, // [64][512] bf16
    const unsigned short* __restrict__ G0tb,   // [64][512] bf16 (G0 transposed)
    const unsigned char* __restrict__ mz1,
    const unsigned char* __restrict__ mz2,
    const unsigned char* __restrict__ mz3,
    float* __restrict__ out)                   // (4096,192), writes cols 128..191
{
    __shared__ __align__(16) unsigned short Rt[2][64 * 512]; // swizzled, no pad
    __shared__ unsigned char m2s[2][512];
    __shared__ unsigned char m3s[2][512];

    const int b0  = blockIdx.x * 2;
    const int tid = threadIdx.x;

    for (int i = tid; i < 1024; i += 512) {
        int bb = i >> 9, k = i & 511;
        m2s[bb][k] = mz2[(size_t)(b0 + bb) * 512 + k];
        m3s[bb][k] = mz3[(size_t)(b0 + bb) * 512 + k];
    }
    #pragma unroll 4
    for (int i = 0; i < 16; ++i) {
        int c = i * 512 + tid;             // 0..8191
        int bb = c >> 12, rem = c & 4095;
        int n = rem >> 6, ch = rem & 63;
        int k = ch * 8;
        s8v g = *(const s8v*)(G0tb + n * 512 + k);
        const unsigned char* mm = mz1 + (size_t)(b0 + bb) * 512 + k;
        unsigned int mlo = *(const unsigned int*)(mm);
        unsigned int mhi = *(const unsigned int*)(mm + 4);
        s8v r;
        #pragma unroll
        for (int j = 0; j < 4; ++j) r[j] = ((mlo >> (8 * j)) & 1) ? g[j] : (short)0;
        #pragma unroll
        for (int j = 0; j < 4; ++j) r[4 + j] = ((mhi >> (8 * j)) & 1) ? g[4 + j] : (short)0;
        *(s8v*)(&Rt[bb][n * 512 + ((ch ^ (n & 7)) << 3)]) = r;
    }
    __syncthreads();

    const int lane = tid & 63, wave = tid >> 6;
    const int q = lane >> 4, ln = lane & 15;
    const int ln7 = ln & 7;

    for (int s = 0; s < 2; ++s) {
        const unsigned short* A = whbf + (size_t)s * 262144;
        f4v acc[2][4][4];
        #pragma unroll
        for (int bb = 0; bb < 2; ++bb)
            #pragma unroll
            for (int mt = 0; mt < 4; ++mt)
                #pragma unroll
                for (int nt = 0; nt < 4; ++nt)
                    acc[bb][mt][nt] = (f4v)(0.0f);

        const unsigned short* Arow = A + (size_t)(wave * 64 + ln) * 512;
        // 2-deep A prefetch: af0 = ks, af1 = ks+1, af2 loads ks+2
        s8v af0[4], af1[4], af2[4];
        #pragma unroll
        for (int mt = 0; mt < 4; ++mt) {
            af0[mt] = *(const s8v*)(Arow + (size_t)(mt * 16) * 512 + q * 8);
            af1[mt] = *(const s8v*)(Arow + (size_t)(mt * 16) * 512 + 32 + q * 8);
        }

        #pragma unroll 2
        for (int ks = 0; ks < 16; ++ks) {
            int kAn = ((ks + 2) & 15) * 32 + q * 8;      // wraps; redundant tail loads
            #pragma unroll
            for (int mt = 0; mt < 4; ++mt)
                af2[mt] = *(const s8v*)(Arow + (size_t)(mt * 16) * 512 + kAn);

            int cB = (ks * 4 + q) ^ ln7;                 // swizzled chunk index
            s8v bfr[2][4];
            #pragma unroll
            for (int bb = 0; bb < 2; ++bb)
                #pragma unroll
                for (int nt = 0; nt < 4; ++nt)
                    bfr[bb][nt] = *(const s8v*)(&Rt[bb][(nt * 16 + ln) * 512 + (cB << 3)]);

            #pragma unroll
            for (int mt = 0; mt < 4; ++mt)
                #pragma unroll
                for (int nt = 0; nt < 4; ++nt) {
                    acc[0][mt][nt] = __builtin_amdgcn_mfma_f32_16x16x32_bf16(af0[mt], bfr[0][nt], acc[0][mt][nt], 0, 0, 0);
                    acc[1][mt][nt] = __builtin_amdgcn_mfma_f32_16x16x32_bf16(af0[mt], bfr[1][nt], acc[1][mt][nt], 0, 0, 0);
                }
            #pragma unroll
            for (int mt = 0; mt < 4; ++mt) {
                af0[mt] = af1[mt];
                af1[mt] = af2[mt];
            }
        }
        __syncthreads();

        const unsigned char (*msk)[512] = (s == 0) ? m2s : m3s;
        #pragma unroll
        for (int bb = 0; bb < 2; ++bb)
            #pragma unroll
            for (int mt = 0; mt < 4; ++mt) {
                int m0 = wave * 64 + mt * 16 + q * 4;    // k-position in new R
                int cw = (wave * 8 + mt * 2 + (q >> 1)); // chunk of m0
                int wo = (q & 1) * 4;                    // short offset in chunk
                uchar4 mv = *(const uchar4*)&msk[bb][m0];
                unsigned char mb[4] = {mv.x, mv.y, mv.z, mv.w};
                #pragma unroll
                for (int nt = 0; nt < 4; ++nt) {
                    int n = nt * 16 + ln;
                    s4v pk;
                    #pragma unroll
                    for (int r = 0; r < 4; ++r) {
                        float v = mb[r] ? acc[bb][mt][nt][r] : 0.0f;
                        pk[r] = (short)f2bf(v);
                    }
                    *(s4v*)(&Rt[bb][n * 512 + ((cw ^ ln7) << 3) + wo]) = pk;
                }
            }
        __syncthreads();
    }

    {
        const int bb = wave >> 2, w4 = wave & 3;
        f4v acc3[4];
        #pragma unroll
        for (int nt = 0; nt < 4; ++nt) acc3[nt] = (f4v)(0.0f);
        for (int ks = 0; ks < 16; ++ks) {
            int kA = ks * 32 + q * 8;
            int cB = (ks * 4 + q) ^ ln7;
            s8v af = *(const s8v*)(woutbf + (size_t)(w4 * 16 + ln) * 512 + kA);
            #pragma unroll
            for (int nt = 0; nt < 4; ++nt) {
                s8v bfr = *(const s8v*)(&Rt[bb][(nt * 16 + ln) * 512 + (cB << 3)]);
                acc3[nt] = __builtin_amdgcn_mfma_f32_16x16x32_bf16(af, bfr, acc3[nt], 0, 0, 0);
            }
        }
        float ss[4];
        #pragma unroll
        for (int r = 0; r < 4; ++r) {
            float s = 0.f;
            #pragma unroll
            for (int nt = 0; nt < 4; ++nt) { float v = acc3[nt][r]; s = fmaf(v, v, s); }
            ss[r] = s;
        }
        #pragma unroll
        for (int off = 1; off < 16; off <<= 1)
            #pragma unroll
            for (int r = 0; r < 4; ++r)
                ss[r] += __shfl_xor(ss[r], off, 64);
        if (ln == 0) {
            #pragma unroll
            for (int r = 0; r < 4; ++r)
                out[(size_t)(b0 + bb) * 192 + 128 + w4 * 16 + q * 4 + r] = sqrtf(ss[r]);
        }
    }
}

// ---------- host ----------
extern "C" void kernel_launch(void* const* d_in, const int* in_sizes, int n_in,
                              void* d_out, int out_size, void* d_ws, size_t ws_size,
                              hipStream_t stream) {
    const float* x    = (const float*)d_in[0];
    const float* Win  = (const float*)d_in[1];
    const float* bin  = (const float*)d_in[2];
    const float* Wh   = (const float*)d_in[3];
    const float* bh   = (const float*)d_in[4];
    const float* Wout = (const float*)d_in[5];
    const float* bout = (const float*)d_in[6];
    float* out = (float*)d_out;

    char* ws = (char*)d_ws;
    unsigned short* whi  = (unsigned short*)(ws);                   // 1703936 B
    unsigned short* wlo  = (unsigned short*)(ws + 1703936);         // 1703936 B
    unsigned short* G0hi = (unsigned short*)(ws + 3407872);         // 65536 B
    unsigned short* G0lo = (unsigned short*)(ws + 3473408);         // 65536 B
    unsigned short* G0tb = (unsigned short*)(ws + 3538944);         // 65536 B
    unsigned char*  masks = (unsigned char*)(ws + 3604480);         // 6 * 2 MB
    unsigned char* mt1 = masks + 0 * 2097152;
    unsigned char* mt2 = masks + 1 * 2097152;
    unsigned char* mt3 = masks + 2 * 2097152;
    unsigned char* mz1 = masks + 3 * 2097152;
    unsigned char* mz2 = masks + 4 * 2097152;
    unsigned char* mz3 = masks + 5 * 2097152;
    float* bufs = (float*)(ws + 3604480 + 12582912);                // 4 x 8 MB
    float* tA = bufs + 0 * 2097152;
    float* tB = bufs + 1 * 2097152;
    float* zA = bufs + 2 * 2097152;
    float* zB = bufs + 3 * 2097152;

    // hi/lo plane offsets (elems): [Win@0 | Wh0@32768 | Wh1@294912 | Wh2@557056 | Wout@819200]
    const unsigned short* WinH  = whi,          *WinL  = wlo;
    const unsigned short* Wh0H  = whi + 32768,  *Wh0L  = wlo + 32768;
    const unsigned short* Wh1H  = whi + 294912, *Wh1L  = wlo + 294912;
    const unsigned short* Wh2H  = whi + 557056, *Wh2L  = wlo + 557056;
    const unsigned short* WoutH = whi + 819200;

    const float* Wh0 = Wh;
    const float* Wh1 = Wh + 262144;
    const float* Wh2 = Wh + 524288;
    const float* bh0 = bh, *bh1 = bh + 512, *bh2 = bh + 1024;

    conv_split<<<dim3(3328), dim3(256), 0, stream>>>(Win, Wh, Wout, whi, wlo);
    g0_kernel<<<dim3(512), dim3(64), 0, stream>>>(Wh0, Win, G0hi, G0lo, G0tb);

    auto gdual = [&](const float* X0, const float* X1, int ldx,
                     const float* W, const unsigned short* WH, const unsigned short* WL, int ldw,
                     const float* bias, float* C0, float* C1, int ldc,
                     unsigned char* mo0, unsigned char* mo1,
                     const unsigned char* mm0, const unsigned char* mm1,
                     int K, int N, int mode) {
        dim3 g(4096 / 128, N / 64, 2);
        gemm_dual<<<g, dim3(512), 0, stream>>>(X0, X1, ldx, W, ldw, WH, WL, bias,
                                               C0, C1, ldc, mo0, mo1, mm0, mm1, K, N, mode);
    };
    auto gemm1 = [&](const float* X, int ldx, const float* W, int ldw, const float* bias,
                     float* C, int ldc, unsigned char* mo, const unsigned char* mm,
                     int K, int N, int mode) {
        dim3 g(4096 / 128, N / 64, 1);
        gemm_nt<<<g, dim3(256), 0, stream>>>(X, ldx, W, ldw, bias, C, ldc, mo, mm, K, N, mode);
    };
    auto g3 = [&](const float* X, int ldx,
                  const unsigned short* WH, const unsigned short* WL, int ldw,
                  float* C, int ldc, const unsigned char* mm, int K, int N, int mode) {
        dim3 g(4096 / 128, N / 64, 1);
        gemm3<<<g, dim3(128), 0, stream>>>(X, ldx, WH, WL, ldw, C, ldc, mm, K, N, mode);
    };

    // ---- fused forward + delta chain (t fp32 ; z split-bf16 MFMA) ----
    gdual(x, x + 128, 192, Win, WinH, WinL, 64, bin, tA, zA, 512, 0, 0, 0, 0, 64, 512, 1 | 4);        // h0
    gdual(tA, zA, 512, Wh0, Wh0H, Wh0L, 512, bh0,   tB, zB, 512, 0, 0, 0, 0, 512, 512, 1 | 2 | 4);    // h1
    gdual(tB, zB, 512, Wh0, Wh0H, Wh0L, 512, bh0,   0, 0, 0, mt1, mz1, 0, 0, 512, 512, 1 | 8);        // delta1
    gdual(tB, zB, 512, Wh1, Wh1H, Wh1L, 512, bh1,   tA, zA, 512, 0, 0, 0, 0, 512, 512, 1 | 2 | 4);    // h2
    gdual(tA, zA, 512, Wh1, Wh1H, Wh1L, 512, bh1,   0, 0, 0, mt2, mz2, 0, 0, 512, 512, 1 | 8);        // delta2
    gdual(tA, zA, 512, Wh2, Wh2H, Wh2L, 512, bh2,   tB, zB, 512, 0, 0, 0, 0, 512, 512, 1 | 2 | 4);    // h3
    gdual(tB, zB, 512, Wh2, Wh2H, Wh2L, 512, bh2,   0, 0, 0, mt3, mz3, 0, 0, 512, 512, 1 | 8);        // delta3

    // ---- zng (z-branch Jacobian row norms), 2 elems/block ----
    zng_kernel<<<dim3(2048), dim3(512), 0, stream>>>(Wh1H, WoutH, G0tb, mz1, mz2, mz3, out);

    // ---- h_out (t-branch forward output) — fp32 ----
    gemm1(tB, 512, Wout, 512, bout, out, 192, 0, 0, 512, 64, 1 | 4);                                  // cols 0..63

    // ---- h_dot chain: V = D (.) (W v) ----
    g3(x + 64, 192, G0hi, G0lo, 64, tA, 512, mt1, 64, 512, 4 | 16);                                   // V1 (split-bf16)
    g3(tA, 512, Wh1H, Wh1L, 512, zA, 512, mt2, 512, 512, 4 | 16);                                     // V2 (split-bf16)
    g3(zA, 512, Wh2H, Wh2L, 512, zB, 512, mt3, 512, 512, 4 | 16);                                     // V3 (split-bf16)
    gemm1(zB, 512, Wout, 512, 0, out + 64, 192, 0, 0, 512, 64, 4);                                    // h_dot (fp32)
}